// Round 10
// baseline (120.033 us; speedup 1.0000x reference)
//
#include <hip/hip_runtime.h>
#include <hip/hip_bf16.h>

typedef __bf16 bf16x8 __attribute__((ext_vector_type(8)));
typedef float f32x16 __attribute__((ext_vector_type(16)));
typedef unsigned int u32;
typedef unsigned short u16;
typedef u32 u32x2 __attribute__((ext_vector_type(2)));
typedef u32 u32x4 __attribute__((ext_vector_type(4)));

static constexpr int Nn  = 2048;
static constexpr int DIN = 129;   // in_features = D_IN+1
static constexpr int QP  = 80;    // padded q/k width (65 -> 80)
static constexpr int AMB = 65;    // ambient dim
static constexpr int XP  = 144;   // padded x row (129 -> 144)
static constexpr int NS  = 4;     // K-splits
static constexpr int PR  = 72;    // partial row pad (65 -> 72), 144 B
// Tiled K/V global layouts == LDS image (gload_lds linear-dest constraint):
static constexpr int KROW = 88;   // K tile row, u16 (176 B)
static constexpr int KTS  = 3072; // K tile size, u16 (6144 B = 6 x 1024B insts)
static constexpr int VROW = 40;   // V tile row, u16 (80 B)
static constexpr int VTS  = 4096; // V tile size, u16 (8192 B = 8 x 1024B insts)
static constexpr float LOG2E = 1.4426950408889634f;

#define DEV static __device__ __forceinline__

#if __has_builtin(__builtin_amdgcn_exp2f)
#define FEXP2 __builtin_amdgcn_exp2f
#else
#define FEXP2 exp2f
#endif

DEV u16 f2bf(float f) {
  union { __bf16 h; u16 u; } c;
  c.h = (__bf16)f;
  return c.u;
}
DEV float bf2f(u16 u) {
  union { float f; u32 uu; } c;
  c.uu = ((u32)u) << 16;
  return c.f;
}
DEV u32 cvtpk(float a, float b) {   // low16 = bf16(a), high16 = bf16(b)
  u32 r;
  asm("v_cvt_pk_bf16_f32 %0, %1, %2" : "=v"(r) : "v"(a), "v"(b));
  return r;
}
DEV void gload_lds16(const u16* g, u16* l) {   // 64 lanes x 16B -> 1024B linear LDS
  __builtin_amdgcn_global_load_lds(
      (const __attribute__((address_space(1))) unsigned int*)g,
      (__attribute__((address_space(3))) unsigned int*)l, 16, 0, 0);
}

// ---------------------------------------------------------------------------
// Prep: x (f32 [8192][129]) -> xb (bf16 [8192][144], zero-padded, 16B-aligned)
// ---------------------------------------------------------------------------
__global__ __launch_bounds__(256) void prep_k(const float* __restrict__ x,
                                              u16* __restrict__ xb) {
  const int t = blockIdx.x * 256 + threadIdx.x;   // 0 .. 8192*18-1
  const int row = t / 18, cg = t % 18;
  u16 tmp[8];
#pragma unroll
  for (int j = 0; j < 8; ++j) {
    const int c = cg * 8 + j;
    tmp[j] = (c < DIN) ? f2bf(x[(size_t)row * DIN + c]) : (u16)0;
  }
  u32x4 w;
  w[0] = (u32)tmp[0] | ((u32)tmp[1] << 16);
  w[1] = (u32)tmp[2] | ((u32)tmp[3] << 16);
  w[2] = (u32)tmp[4] | ((u32)tmp[5] << 16);
  w[3] = (u32)tmp[6] | ((u32)tmp[7] << 16);
  *((u32x4*)xb + t) = w;
}

// ---------------------------------------------------------------------------
// Projection: s = xb @ W[h] + b, lift (C_ATTN=1). Epilogue: scatter into a
// per-wave LDS tile (global-layout image), then coalesced b128 copy-out.
//   Qb:  [bh][n][80] bf16 = alpha' * [qs(64), q0], alpha' = 2*log2e/(scale+eps)
//   Ktl: [bh][tile][key][88] bf16 = [ks(64), -(k0-1), 0*15, junk*8]
//   Vtl: [bh][tile][dim][40] bf16 = col n&31; dims 0-63 vs, 64 v0; rows 65+ junk
// ---------------------------------------------------------------------------
__global__ __launch_bounds__(256) void proj_k(
    const u16* __restrict__ xb,
    const float* __restrict__ Wq, const float* __restrict__ Wk, const float* __restrict__ Wv,
    const float* __restrict__ bq, const float* __restrict__ bk, const float* __restrict__ bv,
    const float* __restrict__ scale_p,
    u16* __restrict__ Qb, u16* __restrict__ Ktl, u16* __restrict__ Vtl) {
  __shared__ u16 wt[64][152];                       // W^T: [d][k]
  __shared__ __align__(16) u16 tiles[4][2816];      // per-wave output tile image

  const int tid = threadIdx.x;
  const int wid = tid >> 6, l = tid & 63;
  const int z = blockIdx.y;            // 0..23
  const int T = z >> 3, h = z & 7;     // tensor (0=Q,1=K,2=V), head
  const float* W    = (T == 0 ? Wq : (T == 1 ? Wk : Wv)) + (size_t)h * DIN * 64;
  const float* bias = (T == 0 ? bq : (T == 1 ? bk : bv)) + h * 64;

  {
    const int d = tid & 63, kk = tid >> 6;
    for (int k = kk; k < XP; k += 4)
      wt[d][k] = (k < DIN) ? f2bf(W[(size_t)k * 64 + d]) : (u16)0;
  }
  __syncthreads();

  const int lo = l & 31, hi = l >> 5;
  const int row0 = (blockIdx.x * 4 + wid) * 32;
  const u16* xr = xb + (size_t)(row0 + lo) * XP;

  f32x16 acc0 = {}, acc1 = {};
#pragma unroll
  for (int s = 0; s < 9; ++s) {
    bf16x8 a  = *(const bf16x8*)&xr[16 * s + 8 * hi];
    bf16x8 b0 = *(const bf16x8*)&wt[lo][16 * s + 8 * hi];
    bf16x8 b1 = *(const bf16x8*)&wt[32 + lo][16 * s + 8 * hi];
    acc0 = __builtin_amdgcn_mfma_f32_32x32x16_bf16(a, b0, acc0, 0, 0, 0);
    acc1 = __builtin_amdgcn_mfma_f32_32x32x16_bf16(a, b1, acc1, 0, 0, 0);
  }
  const float b0v = bias[lo], b1v = bias[32 + lo];
  const float alpha = 2.0f * LOG2E / (scale_p[0] + 1e-7f);
  u16* tl = &tiles[wid][0];

#pragma unroll
  for (int r = 0; r < 16; ++r) {
    const float s0 = acc0[r] + b0v;
    const float s1 = acc1[r] + b1v;
    float part = s0 * s0 + s1 * s1;
#pragma unroll
    for (int m = 1; m < 32; m <<= 1) part += __shfl_xor(part, m);
    const float time = sqrtf(1.0f + part);     // 1/C_ATTN = 1
    const int dr = (r & 3) + 8 * (r >> 2) + 4 * hi;   // row within 32-row tile
    if (T == 0) {
      tl[dr * 80 + lo]      = f2bf(alpha * s0);
      tl[dr * 80 + 32 + lo] = f2bf(alpha * s1);
      if (lo == 0) tl[dr * 80 + 64] = f2bf(alpha * time);
      if (lo < 15) tl[dr * 80 + 65 + lo] = 0;
    } else if (T == 1) {
      tl[dr * 88 + lo]      = f2bf(s0);
      tl[dr * 88 + 32 + lo] = f2bf(s1);
      if (lo == 0) tl[dr * 88 + 64] = f2bf(-(time - 1.0f));  // centered time
      if (lo < 15) tl[dr * 88 + 65 + lo] = 0;
      if (lo < 8)  tl[dr * 88 + 80 + lo] = 0;   // keep copied bytes defined
    } else {
      tl[lo * 40 + dr]        = f2bf(s0);
      tl[(32 + lo) * 40 + dr] = f2bf(s1);
      if (lo == 0) tl[64 * 40 + dr] = f2bf(time);
    }
  }
  __syncthreads();

  // coalesced copy-out: 16B chunks
  const int b = row0 >> 11, n0 = row0 & 2047;
  const int bh = b * 8 + h;
  u16* gdst;
  int nch;
  if (T == 0) { gdst = Qb + ((size_t)bh * Nn + n0) * QP;                nch = 320; }
  else if (T == 1) { gdst = Ktl + (size_t)bh * 64 * KTS + (size_t)(n0 >> 5) * KTS; nch = 352; }
  else { gdst = Vtl + (size_t)bh * 64 * VTS + (size_t)(n0 >> 5) * VTS;  nch = 325; }
  for (int j = l; j < nch; j += 64)
    *(u32x4*)(gdst + j * 8) = *(const u32x4*)(tl + j * 8);
}

// ---------------------------------------------------------------------------
// attn staging: 14 gload_lds insts/tile split 4/4/3/3 across waves
// ---------------------------------------------------------------------------
DEV void stage_tile(const u16* kg, const u16* vg, u16* kl, u16* vl,
                    const int w, const int lane) {
  if (w < 2) {
#pragma unroll
    for (int i = 0; i < 3; ++i)
      gload_lds16(kg + (w * 3 + i) * 512 + lane * 8, kl + (w * 3 + i) * 512);
    gload_lds16(vg + w * 512 + lane * 8, vl + w * 512);
  } else {
#pragma unroll
    for (int i = 0; i < 3; ++i) {
      const int j = (w - 2) * 3 + 2 + i;     // 2..4 / 5..7
      gload_lds16(vg + j * 512 + lane * 8, vl + j * 512);
    }
  }
}

DEV void waitbar() {
  asm volatile("s_waitcnt vmcnt(0) lgkmcnt(0)\ns_barrier" ::: "memory");
}

// QK^T from LDS K + reg Q, exp2, cvt_pk + partner exchange -> P fragments
DEV void qk_exp_pack(const u16* kl, const int lo, const int hi,
                     const bf16x8 (&qf)[5], bf16x8& fA, bf16x8& fB) {
  f32x16 sc = {};
#pragma unroll
  for (int s = 0; s < 5; ++s) {
    const bf16x8 kf = *(const bf16x8*)&kl[lo * KROW + 16 * s + 8 * hi];
    sc = __builtin_amdgcn_mfma_f32_32x32x16_bf16(kf, qf[s], sc, 0, 0, 0);
  }
  float p[16];
#pragma unroll
  for (int r = 0; r < 16; ++r) p[r] = FEXP2(sc[r]);
  u32 wA[4], wB[4];
#pragma unroll
  for (int j = 0; j < 4; ++j) {
    wA[j] = cvtpk(p[2 * j], p[2 * j + 1]);
    wB[j] = cvtpk(p[8 + 2 * j], p[8 + 2 * j + 1]);
  }
  const u32 sA0 = hi ? wA[0] : wA[2], sA1 = hi ? wA[1] : wA[3];
  const u32 sB0 = hi ? wB[0] : wB[2], sB1 = hi ? wB[1] : wB[3];
  const u32 rA0 = (u32)__shfl_xor((int)sA0, 32);
  const u32 rA1 = (u32)__shfl_xor((int)sA1, 32);
  const u32 rB0 = (u32)__shfl_xor((int)sB0, 32);
  const u32 rB1 = (u32)__shfl_xor((int)sB1, 32);
  u32x4 ua = hi ? (u32x4){rA0, rA1, wA[2], wA[3]}
                : (u32x4){wA[0], wA[1], rA0, rA1};
  u32x4 ub = hi ? (u32x4){rB0, rB1, wB[2], wB[3]}
                : (u32x4){wB[0], wB[1], rB0, rB1};
  union { u32x4 u; bf16x8 b; } ca, cb;
  ca.u = ua; cb.u = ub;
  fA = ca.b;   // keys +0..15
  fB = cb.b;   // keys +16..31
}

DEV void loadV(const u16* vl, const int lo, const int hi, bf16x8 (&vr)[6]) {
#pragma unroll
  for (int t = 0; t < 3; ++t) {
    vr[2 * t]     = *(const bf16x8*)&vl[(32 * t + lo) * VROW + 8 * hi];
    vr[2 * t + 1] = *(const bf16x8*)&vl[(32 * t + lo) * VROW + 16 + 8 * hi];
  }
}

DEV void pv(const bf16x8 (&vr)[6], const bf16x8 fA, const bf16x8 fB,
            f32x16& o0, f32x16& o1, f32x16& o2) {
  o0 = __builtin_amdgcn_mfma_f32_32x32x16_bf16(vr[0], fA, o0, 0, 0, 0);
  o0 = __builtin_amdgcn_mfma_f32_32x32x16_bf16(vr[1], fB, o0, 0, 0, 0);
  o1 = __builtin_amdgcn_mfma_f32_32x32x16_bf16(vr[2], fA, o1, 0, 0, 0);
  o1 = __builtin_amdgcn_mfma_f32_32x32x16_bf16(vr[3], fB, o1, 0, 0, 0);
  o2 = __builtin_amdgcn_mfma_f32_32x32x16_bf16(vr[4], fA, o2, 0, 0, 0);
  o2 = __builtin_amdgcn_mfma_f32_32x32x16_bf16(vr[5], fB, o2, 0, 0, 0);
}

// ---------------------------------------------------------------------------
// Attention: software-pipelined intervals. Interval i: stage(i+1) || V(i)->regs
// || PV(i-1) [pure-reg MFMA, no dep on this interval's loads] || QK(i)+exp+pack.
// 2 LDS buffers, fully static indexing (unroll-2 + peeled ends).
// 4 waves/block, 1 wave = 32 q, swapped QK^T. XCD swizzle. S=4 splits.
// ---------------------------------------------------------------------------
__global__ __launch_bounds__(256) void attn_k(
    const u16* __restrict__ Qb, const u16* __restrict__ Ktl,
    const u16* __restrict__ Vtl, u16* __restrict__ part) {
  __shared__ u16 kls[2][KTS];
  __shared__ u16 vls[2][VTS];

  const int tid  = threadIdx.x;
  const int w    = tid >> 6, lane = tid & 63;
  const int lo   = lane & 31, hi = lane >> 5;

  // XCD-chunked swizzle (2048 blocks, 8 XCDs, bijective): 4 whole bh per XCD
  const u32 bid = blockIdx.x;
  const u32 swz = (bid & 7) * 256 + (bid >> 3);
  const int bh   = swz >> 6;
  const int sidx = (swz >> 4) & 3;
  const int qt   = swz & 15;
  const int qbase = qt * 128 + w * 32;

  const u16* qrow = Qb + ((size_t)bh * Nn + qbase + lo) * QP;
  bf16x8 qf[5];
#pragma unroll
  for (int s = 0; s < 5; ++s) qf[s] = *(const bf16x8*)&qrow[16 * s + 8 * hi];

  f32x16 o0 = {}, o1 = {}, o2 = {};   // O^T rows d = 0..31, 32..63, 64..95
  const u16* ktb = Ktl + (size_t)bh * 64 * KTS + (size_t)(sidx * 16) * KTS;
  const u16* vtb = Vtl + (size_t)bh * 64 * VTS + (size_t)(sidx * 16) * VTS;

  bf16x8 vA[6], vB[6], fA0, fB0, fA1, fB1;

  // prologue: stage tile 0 -> buf0, drain, then interval 0
  stage_tile(ktb, vtb, kls[0], vls[0], w, lane);
  waitbar();

  // interval 0: stage 1->buf1; vA <- V(0); QK(0) -> f0; no PV
  stage_tile(ktb + KTS, vtb + VTS, kls[1], vls[1], w, lane);
  loadV(vls[0], lo, hi, vA);
  qk_exp_pack(kls[0], lo, hi, qf, fA0, fB0);
  waitbar();

#pragma unroll 1
  for (int i = 1; i <= 13; i += 2) {
    // interval i (odd): cur buf1; stage (i+1)->buf0; vB<-V(i); PV(i-1); QK(i)->f1
    stage_tile(ktb + (size_t)(i + 1) * KTS, vtb + (size_t)(i + 1) * VTS,
               kls[0], vls[0], w, lane);
    loadV(vls[1], lo, hi, vB);
    pv(vA, fA0, fB0, o0, o1, o2);
    qk_exp_pack(kls[1], lo, hi, qf, fA1, fB1);
    waitbar();
    // interval i+1 (even): cur buf0; stage (i+2)->buf1; vA<-V(i+1); PV(i); QK(i+1)->f0
    stage_tile(ktb + (size_t)(i + 2) * KTS, vtb + (size_t)(i + 2) * VTS,
               kls[1], vls[1], w, lane);
    loadV(vls[0], lo, hi, vA);
    pv(vB, fA1, fB1, o0, o1, o2);
    qk_exp_pack(kls[0], lo, hi, qf, fA0, fB0);
    waitbar();
  }
  // interval 15 (odd): cur buf1; no stage; vB<-V(15); PV(14); QK(15)->f1
  loadV(vls[1], lo, hi, vB);
  pv(vA, fA0, fB0, o0, o1, o2);
  qk_exp_pack(kls[1], lo, hi, qf, fA1, fB1);
  // epilogue: PV(15)
  pv(vB, fA1, fB1, o0, o1, o2);

  // write raw partial O^T, d-contiguous rows: lane owns q = qbase+lo.
  const int q = qbase + lo;
  u16* po = part + ((size_t)((bh * NS + sidx) * Nn + q)) * PR;
#pragma unroll
  for (int t = 0; t < 4; ++t) {
    const u32 a0 = cvtpk(o0[4 * t], o0[4 * t + 1]);
    const u32 a1 = cvtpk(o0[4 * t + 2], o0[4 * t + 3]);
    const u32 b0 = cvtpk(o1[4 * t], o1[4 * t + 1]);
    const u32 b1 = cvtpk(o1[4 * t + 2], o1[4 * t + 3]);
    *(u32x2*)&po[8 * t + 4 * hi]      = (u32x2){a0, a1};
    *(u32x2*)&po[8 * t + 4 * hi + 32] = (u32x2){b0, b1};
  }
  if (hi == 0) po[64] = f2bf(o2[0]);
}

// ---------------------------------------------------------------------------
// Finale (wave-cooperative): one wave per (b,n). Lane l -> (h = l>>3, chunk
// c = l&7). Combine 4 splits, per-head Lorentz normalize (shfl_xor 1,2,4),
// head-sum (shfl_xor 8,16,32), final normalize + re-lift.
// ---------------------------------------------------------------------------
__global__ __launch_bounds__(256) void finale_k(const u16* __restrict__ part,
                                                float* __restrict__ out) {
  const int tid = threadIdx.x;
  const int wv = tid >> 6, l = tid & 63;
  const int g = blockIdx.x * 4 + wv;       // 0..8191 = b*2048+n
  const int b = g >> 11, n = g & 2047;
  const int h = l >> 3, c = l & 7;

  const u16* rowp = part + ((size_t)((b * 8 + h) * NS) * Nn + n) * PR;
  float Oh[8];
#pragma unroll
  for (int j = 0; j < 8; ++j) Oh[j] = 0.f;
  float th = 0.f;
#pragma unroll
  for (int s = 0; s < NS; ++s) {
    const u16* rp = rowp + (size_t)s * Nn * PR;
    const u32x4 v = *(const u32x4*)&rp[8 * c];
#pragma unroll
    for (int i = 0; i < 4; ++i) {
      union { u32 u; float f; } a, bb;
      a.u  = v[i] << 16;
      bb.u = v[i] & 0xffff0000u;
      Oh[2 * i]     += a.f;
      Oh[2 * i + 1] += bb.f;
    }
    th += bf2f(rp[64]);
  }

  float sq = 0.f;
#pragma unroll
  for (int j = 0; j < 8; ++j) sq += Oh[j] * Oh[j];
  sq += __shfl_xor(sq, 1);
  sq += __shfl_xor(sq, 2);
  sq += __shfl_xor(sq, 4);
  const float invh = rsqrtf(fmaxf(th * th - sq, 1e-7f));

  float S[8];
#pragma unroll
  for (int j = 0; j < 8; ++j) S[j] = Oh[j] * invh;
  float T = th * invh;
#pragma unroll
  for (int m = 8; m <= 32; m <<= 1) {
#pragma unroll
    for (int j = 0; j < 8; ++j) S[j] += __shfl_xor(S[j], m);
    T += __shfl_xor(T, m);
  }

  float s2 = 0.f;
#pragma unroll
  for (int j = 0; j < 8; ++j) s2 += S[j] * S[j];
  s2 += __shfl_xor(s2, 1);
  s2 += __shfl_xor(s2, 2);
  s2 += __shfl_xor(s2, 4);
  const float inv = rsqrtf(fmaxf(T * T - s2, 1e-7f));
  const float ssp = s2 * inv * inv;        // ||spatial_out||^2

  float* o = out + (size_t)g * AMB;
  if (h == 0) {
#pragma unroll
    for (int j = 0; j < 8; ++j) o[1 + 8 * c + j] = S[j] * inv;
    if (l == 0) o[0] = sqrtf(1.0f + ssp);
  }
}

// ---------------------------------------------------------------------------
extern "C" void kernel_launch(void* const* d_in, const int* in_sizes, int n_in,
                              void* d_out, int out_size, void* d_ws, size_t ws_size,
                              hipStream_t stream) {
  (void)in_sizes; (void)n_in; (void)out_size; (void)ws_size;
  const float* x  = (const float*)d_in[0];
  const float* Wq = (const float*)d_in[1];
  const float* Wk = (const float*)d_in[2];
  const float* Wv = (const float*)d_in[3];
  const float* bq = (const float*)d_in[4];
  const float* bk = (const float*)d_in[5];
  const float* bv = (const float*)d_in[6];
  const float* sc = (const float*)d_in[7];
  // d_in[8] = attn_bias: uniform additive score offset -> softmax-invariant.

  char* ws = (char*)d_ws;
  u16*  Qb  = (u16*)(ws);                  // 10,485,760 B
  u16*  Ktl = (u16*)(ws + 10485760);       // 32*64*6144 = 12,582,912 B
  u16*  Vtl = (u16*)(ws + 23068672);       // 32*64*8192 = 16,777,216 B
  u16*  pb  = (u16*)(ws + 39845888);       // bf16 partials: 37,748,736 B -> end 77.6 MB
  u16*  xb  = (u16*)(ws + 39845888);       // 2,359,296 B overlay, dead before attn_k
  float* out = (float*)d_out;

  hipLaunchKernelGGL(prep_k, dim3(576), dim3(256), 0, stream, x, xb);
  hipLaunchKernelGGL(proj_k, dim3(64, 24), dim3(256), 0, stream,
                     xb, Wq, Wk, Wv, bq, bk, bv, sc, Qb, Ktl, Vtl);
  hipLaunchKernelGGL(attn_k, dim3(2048), dim3(256), 0, stream, Qb, Ktl, Vtl, pb);
  hipLaunchKernelGGL(finale_k, dim3(2048), dim3(256), 0, stream, pb, out);
}

// Round 11
// 111.287 us; speedup vs baseline: 1.0786x; 1.0786x over previous
//
#include <hip/hip_runtime.h>
#include <hip/hip_bf16.h>

typedef __bf16 bf16x8 __attribute__((ext_vector_type(8)));
typedef float f32x16 __attribute__((ext_vector_type(16)));
typedef unsigned int u32;
typedef unsigned short u16;
typedef u32 u32x2 __attribute__((ext_vector_type(2)));
typedef u32 u32x4 __attribute__((ext_vector_type(4)));

static constexpr int Nn  = 2048;
static constexpr int DIN = 129;   // in_features = D_IN+1
static constexpr int QP  = 80;    // padded q/k width (65 -> 80)
static constexpr int AMB = 65;    // ambient dim
static constexpr int XP  = 144;   // padded x row (129 -> 144)
static constexpr int NS  = 4;     // K-splits
static constexpr int PR  = 72;    // partial row pad (65 -> 72), 144 B
// Tiled K/V global layouts == LDS image (gload_lds linear-dest constraint):
static constexpr int KROW = 88;   // K tile row, u16 (176 B)
static constexpr int KTS  = 3072; // K tile size, u16 (6144 B = 6 x 1024B insts)
static constexpr int VROW = 40;   // V tile row, u16 (80 B)
static constexpr int VTS  = 4096; // V tile size, u16 (8192 B = 8 x 1024B insts)
static constexpr float LOG2E = 1.4426950408889634f;

#define DEV static __device__ __forceinline__

#if __has_builtin(__builtin_amdgcn_exp2f)
#define FEXP2 __builtin_amdgcn_exp2f
#else
#define FEXP2 exp2f
#endif

DEV u16 f2bf(float f) {
  union { __bf16 h; u16 u; } c;
  c.h = (__bf16)f;
  return c.u;
}
DEV float bf2f(u16 u) {
  union { float f; u32 uu; } c;
  c.uu = ((u32)u) << 16;
  return c.f;
}
DEV u32 cvtpk(float a, float b) {   // low16 = bf16(a), high16 = bf16(b)
  u32 r;
  asm("v_cvt_pk_bf16_f32 %0, %1, %2" : "=v"(r) : "v"(a), "v"(b));
  return r;
}
DEV void gload_lds16(const u16* g, u16* l) {   // 64 lanes x 16B -> 1024B linear LDS
  __builtin_amdgcn_global_load_lds(
      (const __attribute__((address_space(1))) unsigned int*)g,
      (__attribute__((address_space(3))) unsigned int*)l, 16, 0, 0);
}

// ---------------------------------------------------------------------------
// Prep: x (f32 [8192][129]) -> xb (bf16 [8192][144], zero-padded, 16B-aligned)
// ---------------------------------------------------------------------------
__global__ __launch_bounds__(256) void prep_k(const float* __restrict__ x,
                                              u16* __restrict__ xb) {
  const int t = blockIdx.x * 256 + threadIdx.x;   // 0 .. 8192*18-1
  const int row = t / 18, cg = t % 18;
  u16 tmp[8];
#pragma unroll
  for (int j = 0; j < 8; ++j) {
    const int c = cg * 8 + j;
    tmp[j] = (c < DIN) ? f2bf(x[(size_t)row * DIN + c]) : (u16)0;
  }
  u32x4 w;
  w[0] = (u32)tmp[0] | ((u32)tmp[1] << 16);
  w[1] = (u32)tmp[2] | ((u32)tmp[3] << 16);
  w[2] = (u32)tmp[4] | ((u32)tmp[5] << 16);
  w[3] = (u32)tmp[6] | ((u32)tmp[7] << 16);
  *((u32x4*)xb + t) = w;
}

// ---------------------------------------------------------------------------
// Projection: s = xb @ W[h] + b, lift (C_ATTN=1). Epilogue: scatter into a
// per-wave LDS tile (global-layout image), then coalesced b128 copy-out.
//   Qb:  [bh][n][80] bf16 = alpha' * [qs(64), q0], alpha' = 2*log2e/(scale+eps)
//   Ktl: [bh][tile][key][88] bf16 = [ks(64), -(k0-1), 0*15, junk*8]
//   Vtl: [bh][tile][dim][40] bf16 = col n&31; dims 0-63 vs, 64 v0; rows 65+ junk
// ---------------------------------------------------------------------------
__global__ __launch_bounds__(256) void proj_k(
    const u16* __restrict__ xb,
    const float* __restrict__ Wq, const float* __restrict__ Wk, const float* __restrict__ Wv,
    const float* __restrict__ bq, const float* __restrict__ bk, const float* __restrict__ bv,
    const float* __restrict__ scale_p,
    u16* __restrict__ Qb, u16* __restrict__ Ktl, u16* __restrict__ Vtl) {
  __shared__ u16 wt[64][152];                       // W^T: [d][k]
  __shared__ __align__(16) u16 tiles[4][2816];      // per-wave output tile image

  const int tid = threadIdx.x;
  const int wid = tid >> 6, l = tid & 63;
  const int z = blockIdx.y;            // 0..23
  const int T = z >> 3, h = z & 7;     // tensor (0=Q,1=K,2=V), head
  const float* W    = (T == 0 ? Wq : (T == 1 ? Wk : Wv)) + (size_t)h * DIN * 64;
  const float* bias = (T == 0 ? bq : (T == 1 ? bk : bv)) + h * 64;

  {
    const int d = tid & 63, kk = tid >> 6;
    for (int k = kk; k < XP; k += 4)
      wt[d][k] = (k < DIN) ? f2bf(W[(size_t)k * 64 + d]) : (u16)0;
  }
  __syncthreads();

  const int lo = l & 31, hi = l >> 5;
  const int row0 = (blockIdx.x * 4 + wid) * 32;
  const u16* xr = xb + (size_t)(row0 + lo) * XP;

  f32x16 acc0 = {}, acc1 = {};
#pragma unroll
  for (int s = 0; s < 9; ++s) {
    bf16x8 a  = *(const bf16x8*)&xr[16 * s + 8 * hi];
    bf16x8 b0 = *(const bf16x8*)&wt[lo][16 * s + 8 * hi];
    bf16x8 b1 = *(const bf16x8*)&wt[32 + lo][16 * s + 8 * hi];
    acc0 = __builtin_amdgcn_mfma_f32_32x32x16_bf16(a, b0, acc0, 0, 0, 0);
    acc1 = __builtin_amdgcn_mfma_f32_32x32x16_bf16(a, b1, acc1, 0, 0, 0);
  }
  const float b0v = bias[lo], b1v = bias[32 + lo];
  const float alpha = 2.0f * LOG2E / (scale_p[0] + 1e-7f);
  u16* tl = &tiles[wid][0];

#pragma unroll
  for (int r = 0; r < 16; ++r) {
    const float s0 = acc0[r] + b0v;
    const float s1 = acc1[r] + b1v;
    float part = s0 * s0 + s1 * s1;
#pragma unroll
    for (int m = 1; m < 32; m <<= 1) part += __shfl_xor(part, m);
    const float time = sqrtf(1.0f + part);     // 1/C_ATTN = 1
    const int dr = (r & 3) + 8 * (r >> 2) + 4 * hi;   // row within 32-row tile
    if (T == 0) {
      tl[dr * 80 + lo]      = f2bf(alpha * s0);
      tl[dr * 80 + 32 + lo] = f2bf(alpha * s1);
      if (lo == 0) tl[dr * 80 + 64] = f2bf(alpha * time);
      if (lo < 15) tl[dr * 80 + 65 + lo] = 0;
    } else if (T == 1) {
      tl[dr * 88 + lo]      = f2bf(s0);
      tl[dr * 88 + 32 + lo] = f2bf(s1);
      if (lo == 0) tl[dr * 88 + 64] = f2bf(-(time - 1.0f));  // centered time
      if (lo < 15) tl[dr * 88 + 65 + lo] = 0;
      if (lo < 8)  tl[dr * 88 + 80 + lo] = 0;   // keep copied bytes defined
    } else {
      tl[lo * 40 + dr]        = f2bf(s0);
      tl[(32 + lo) * 40 + dr] = f2bf(s1);
      if (lo == 0) tl[64 * 40 + dr] = f2bf(time);
    }
  }
  __syncthreads();

  // coalesced copy-out: 16B chunks
  const int b = row0 >> 11, n0 = row0 & 2047;
  const int bh = b * 8 + h;
  u16* gdst;
  int nch;
  if (T == 0) { gdst = Qb + ((size_t)bh * Nn + n0) * QP;                nch = 320; }
  else if (T == 1) { gdst = Ktl + (size_t)bh * 64 * KTS + (size_t)(n0 >> 5) * KTS; nch = 352; }
  else { gdst = Vtl + (size_t)bh * 64 * VTS + (size_t)(n0 >> 5) * VTS;  nch = 325; }
  for (int j = l; j < nch; j += 64)
    *(u32x4*)(gdst + j * 8) = *(const u32x4*)(tl + j * 8);
}

// ---------------------------------------------------------------------------
// attn staging: 14 gload_lds insts/tile split 4/4/3/3 across waves
// ---------------------------------------------------------------------------
DEV void stage_tile(const u16* kg, const u16* vg, u16* kl, u16* vl,
                    const int w, const int lane) {
  if (w < 2) {
#pragma unroll
    for (int i = 0; i < 3; ++i)
      gload_lds16(kg + (w * 3 + i) * 512 + lane * 8, kl + (w * 3 + i) * 512);
    gload_lds16(vg + w * 512 + lane * 8, vl + w * 512);
  } else {
#pragma unroll
    for (int i = 0; i < 3; ++i) {
      const int j = (w - 2) * 3 + 2 + i;     // 2..4 / 5..7
      gload_lds16(vg + j * 512 + lane * 8, vl + j * 512);
    }
  }
}

// T4 counted-vmcnt barrier: leave the newest tile's own loads (4 or 3) in
// flight, drain everything older + all lgkm.
DEV void waitbar(const int w) {
  if (w < 2)
    asm volatile("s_waitcnt vmcnt(4) lgkmcnt(0)\ns_barrier" ::: "memory");
  else
    asm volatile("s_waitcnt vmcnt(3) lgkmcnt(0)\ns_barrier" ::: "memory");
}

// exp2 + cvt_pk + partner exchange: scores (one 32-q half) -> P fragments
DEV void exp_pack(const f32x16 sc, const int hi, bf16x8& fA, bf16x8& fB) {
  float p[16];
#pragma unroll
  for (int r = 0; r < 16; ++r) p[r] = FEXP2(sc[r]);
  u32 wA[4], wB[4];
#pragma unroll
  for (int j = 0; j < 4; ++j) {
    wA[j] = cvtpk(p[2 * j], p[2 * j + 1]);
    wB[j] = cvtpk(p[8 + 2 * j], p[8 + 2 * j + 1]);
  }
  const u32 sA0 = hi ? wA[0] : wA[2], sA1 = hi ? wA[1] : wA[3];
  const u32 sB0 = hi ? wB[0] : wB[2], sB1 = hi ? wB[1] : wB[3];
  const u32 rA0 = (u32)__shfl_xor((int)sA0, 32);
  const u32 rA1 = (u32)__shfl_xor((int)sA1, 32);
  const u32 rB0 = (u32)__shfl_xor((int)sB0, 32);
  const u32 rB1 = (u32)__shfl_xor((int)sB1, 32);
  u32x4 ua = hi ? (u32x4){rA0, rA1, wA[2], wA[3]}
                : (u32x4){wA[0], wA[1], rA0, rA1};
  u32x4 ub = hi ? (u32x4){rB0, rB1, wB[2], wB[3]}
                : (u32x4){wB[0], wB[1], rB0, rB1};
  union { u32x4 u; bf16x8 b; } ca, cb;
  ca.u = ua; cb.u = ub;
  fA = ca.b;   // keys +0..15
  fB = cb.b;   // keys +16..31
}

// ---------------------------------------------------------------------------
// One 32-key tile for 64 q-rows: every K/V ds_read feeds 2 MFMA (half A: q
// cols qbase+0..31, half B: qbase+32..63). 22 MFMA / 11 b128 ds_reads.
// ---------------------------------------------------------------------------
DEV void compute_tile64(const u16* kl, const u16* vl, const int lo, const int hi,
                        const bf16x8 (&qA)[5], const bf16x8 (&qB)[5],
                        f32x16& a0, f32x16& a1, f32x16& a2,
                        f32x16& b0, f32x16& b1, f32x16& b2) {
  f32x16 sA = {}, sB = {};
#pragma unroll
  for (int s = 0; s < 5; ++s) {
    const bf16x8 kf = *(const bf16x8*)&kl[lo * KROW + 16 * s + 8 * hi];
    sA = __builtin_amdgcn_mfma_f32_32x32x16_bf16(kf, qA[s], sA, 0, 0, 0);
    sB = __builtin_amdgcn_mfma_f32_32x32x16_bf16(kf, qB[s], sB, 0, 0, 0);
  }
  bf16x8 fA0, fB0, fA1, fB1;
  exp_pack(sA, hi, fA0, fB0);
  exp_pack(sB, hi, fA1, fB1);
#pragma unroll
  for (int t = 0; t < 3; ++t) {
    const bf16x8 va = *(const bf16x8*)&vl[(32 * t + lo) * VROW + 8 * hi];
    const bf16x8 vb = *(const bf16x8*)&vl[(32 * t + lo) * VROW + 16 + 8 * hi];
    f32x16& oa = (t == 0 ? a0 : (t == 1 ? a1 : a2));
    f32x16& ob = (t == 0 ? b0 : (t == 1 ? b1 : b2));
    oa = __builtin_amdgcn_mfma_f32_32x32x16_bf16(va, fA0, oa, 0, 0, 0);
    oa = __builtin_amdgcn_mfma_f32_32x32x16_bf16(vb, fB0, oa, 0, 0, 0);
    ob = __builtin_amdgcn_mfma_f32_32x32x16_bf16(va, fA1, ob, 0, 0, 0);
    ob = __builtin_amdgcn_mfma_f32_32x32x16_bf16(vb, fB1, ob, 0, 0, 0);
  }
}

DEV void write_partial(u16* part, const int bh, const int sidx, const int q,
                       const int hi, const f32x16& o0, const f32x16& o1,
                       const f32x16& o2) {
  u16* po = part + ((size_t)((bh * NS + sidx) * Nn + q)) * PR;
#pragma unroll
  for (int t = 0; t < 4; ++t) {
    const u32 a0 = cvtpk(o0[4 * t], o0[4 * t + 1]);
    const u32 a1 = cvtpk(o0[4 * t + 2], o0[4 * t + 3]);
    const u32 b0 = cvtpk(o1[4 * t], o1[4 * t + 1]);
    const u32 b1 = cvtpk(o1[4 * t + 2], o1[4 * t + 3]);
    *(u32x2*)&po[8 * t + 4 * hi]      = (u32x2){a0, a1};
    *(u32x2*)&po[8 * t + 4 * hi + 32] = (u32x2){b0, b1};
  }
  if (hi == 0) po[64] = f2bf(o2[0]);
}

// ---------------------------------------------------------------------------
// Attention: 64 q/wave (2 fragment sets share all K/V reads), 3-buffer LDS,
// depth-2 prefetch, counted vmcnt. 4 waves/block = 256 q. XCD swizzle.
// Grid 1024 = 32 bh x 4 splits x 8 qt.
// ---------------------------------------------------------------------------
__global__ __launch_bounds__(256, 2) void attn_k(
    const u16* __restrict__ Qb, const u16* __restrict__ Ktl,
    const u16* __restrict__ Vtl, u16* __restrict__ part) {
  __shared__ u16 kls[3][KTS];
  __shared__ u16 vls[3][VTS];

  const int tid  = threadIdx.x;
  const int w    = tid >> 6, lane = tid & 63;
  const int lo   = lane & 31, hi = lane >> 5;

  // XCD-chunked swizzle (1024 blocks, 8 XCDs, bijective): 4 whole bh per XCD
  const u32 bid = blockIdx.x;
  const u32 swz = (bid & 7) * 128 + (bid >> 3);
  const int bh   = swz >> 5;
  const int sidx = (swz >> 3) & 3;
  const int qt   = swz & 7;
  const int qbase = qt * 256 + w * 64;

  const u16* qrowA = Qb + ((size_t)bh * Nn + qbase + lo) * QP;
  const u16* qrowB = qrowA + 32 * QP;
  bf16x8 qA[5], qB[5];
#pragma unroll
  for (int s = 0; s < 5; ++s) {
    qA[s] = *(const bf16x8*)&qrowA[16 * s + 8 * hi];
    qB[s] = *(const bf16x8*)&qrowB[16 * s + 8 * hi];
  }

  f32x16 a0 = {}, a1 = {}, a2 = {};   // half A: O^T d rows, q cols qbase+lo
  f32x16 b0 = {}, b1 = {}, b2 = {};   // half B: q cols qbase+32+lo
  const u16* ktb = Ktl + (size_t)bh * 64 * KTS + (size_t)(sidx * 16) * KTS;
  const u16* vtb = Vtl + (size_t)bh * 64 * VTS + (size_t)(sidx * 16) * VTS;

  // prologue: prefetch tiles 0 and 1
  stage_tile(ktb, vtb, kls[0], vls[0], w, lane);
  stage_tile(ktb + KTS, vtb + VTS, kls[1], vls[1], w, lane);
  waitbar(w);   // tile 0 landed; tile 1 in flight

#pragma unroll 1
  for (int t = 0; t < 16; ++t) {
    const int pf = (t + 2 < 16) ? t + 2 : 15;   // clamp: redundant restage keeps vmcnt uniform
    stage_tile(ktb + (size_t)pf * KTS, vtb + (size_t)pf * VTS,
               kls[(t + 2) % 3], vls[(t + 2) % 3], w, lane);
    compute_tile64(kls[t % 3], vls[t % 3], lo, hi, qA, qB, a0, a1, a2, b0, b1, b2);
    waitbar(w);  // tile t+1 landed; tile t+2 in flight
  }

  write_partial(part, bh, sidx, qbase + lo,      hi, a0, a1, a2);
  write_partial(part, bh, sidx, qbase + 32 + lo, hi, b0, b1, b2);
}

// ---------------------------------------------------------------------------
// Finale (wave-cooperative): one wave per (b,n). Lane l -> (h = l>>3, chunk
// c = l&7). Combine 4 splits, per-head Lorentz normalize (shfl_xor 1,2,4),
// head-sum (shfl_xor 8,16,32), final normalize + re-lift.
// ---------------------------------------------------------------------------
__global__ __launch_bounds__(256) void finale_k(const u16* __restrict__ part,
                                                float* __restrict__ out) {
  const int tid = threadIdx.x;
  const int wv = tid >> 6, l = tid & 63;
  const int g = blockIdx.x * 4 + wv;       // 0..8191 = b*2048+n
  const int b = g >> 11, n = g & 2047;
  const int h = l >> 3, c = l & 7;

  const u16* rowp = part + ((size_t)((b * 8 + h) * NS) * Nn + n) * PR;
  float Oh[8];
#pragma unroll
  for (int j = 0; j < 8; ++j) Oh[j] = 0.f;
  float th = 0.f;
#pragma unroll
  for (int s = 0; s < NS; ++s) {
    const u16* rp = rowp + (size_t)s * Nn * PR;
    const u32x4 v = *(const u32x4*)&rp[8 * c];
#pragma unroll
    for (int i = 0; i < 4; ++i) {
      union { u32 u; float f; } a, bb;
      a.u  = v[i] << 16;
      bb.u = v[i] & 0xffff0000u;
      Oh[2 * i]     += a.f;
      Oh[2 * i + 1] += bb.f;
    }
    th += bf2f(rp[64]);
  }

  float sq = 0.f;
#pragma unroll
  for (int j = 0; j < 8; ++j) sq += Oh[j] * Oh[j];
  sq += __shfl_xor(sq, 1);
  sq += __shfl_xor(sq, 2);
  sq += __shfl_xor(sq, 4);
  const float invh = rsqrtf(fmaxf(th * th - sq, 1e-7f));

  float S[8];
#pragma unroll
  for (int j = 0; j < 8; ++j) S[j] = Oh[j] * invh;
  float T = th * invh;
#pragma unroll
  for (int m = 8; m <= 32; m <<= 1) {
#pragma unroll
    for (int j = 0; j < 8; ++j) S[j] += __shfl_xor(S[j], m);
    T += __shfl_xor(T, m);
  }

  float s2 = 0.f;
#pragma unroll
  for (int j = 0; j < 8; ++j) s2 += S[j] * S[j];
  s2 += __shfl_xor(s2, 1);
  s2 += __shfl_xor(s2, 2);
  s2 += __shfl_xor(s2, 4);
  const float inv = rsqrtf(fmaxf(T * T - s2, 1e-7f));
  const float ssp = s2 * inv * inv;        // ||spatial_out||^2

  float* o = out + (size_t)g * AMB;
  if (h == 0) {
#pragma unroll
    for (int j = 0; j < 8; ++j) o[1 + 8 * c + j] = S[j] * inv;
    if (l == 0) o[0] = sqrtf(1.0f + ssp);
  }
}

// ---------------------------------------------------------------------------
extern "C" void kernel_launch(void* const* d_in, const int* in_sizes, int n_in,
                              void* d_out, int out_size, void* d_ws, size_t ws_size,
                              hipStream_t stream) {
  (void)in_sizes; (void)n_in; (void)out_size; (void)ws_size;
  const float* x  = (const float*)d_in[0];
  const float* Wq = (const float*)d_in[1];
  const float* Wk = (const float*)d_in[2];
  const float* Wv = (const float*)d_in[3];
  const float* bq = (const float*)d_in[4];
  const float* bk = (const float*)d_in[5];
  const float* bv = (const float*)d_in[6];
  const float* sc = (const float*)d_in[7];
  // d_in[8] = attn_bias: uniform additive score offset -> softmax-invariant.

  char* ws = (char*)d_ws;
  u16*  Qb  = (u16*)(ws);                  // 10,485,760 B
  u16*  Ktl = (u16*)(ws + 10485760);       // 32*64*6144 = 12,582,912 B
  u16*  Vtl = (u16*)(ws + 23068672);       // 32*64*8192 = 16,777,216 B
  u16*  pb  = (u16*)(ws + 39845888);       // bf16 partials: 37,748,736 B -> end 77.6 MB
  u16*  xb  = (u16*)(ws + 39845888);       // 2,359,296 B overlay, dead before attn_k
  float* out = (float*)d_out;

  hipLaunchKernelGGL(prep_k, dim3(576), dim3(256), 0, stream, x, xb);
  hipLaunchKernelGGL(proj_k, dim3(64, 24), dim3(256), 0, stream,
                     xb, Wq, Wk, Wv, bq, bk, bv, sc, Qb, Ktl, Vtl);
  hipLaunchKernelGGL(attn_k, dim3(1024), dim3(256), 0, stream, Qb, Ktl, Vtl, pb);
  hipLaunchKernelGGL(finale_k, dim3(2048), dim3(256), 0, stream, pb, out);
}

// Round 12
// 102.195 us; speedup vs baseline: 1.1746x; 1.0890x over previous
//
#include <hip/hip_runtime.h>
#include <hip/hip_bf16.h>

typedef __bf16 bf16x8 __attribute__((ext_vector_type(8)));
typedef float f32x16 __attribute__((ext_vector_type(16)));
typedef unsigned int u32;
typedef unsigned short u16;
typedef u32 u32x2 __attribute__((ext_vector_type(2)));
typedef u32 u32x4 __attribute__((ext_vector_type(4)));

static constexpr int Nn  = 2048;
static constexpr int DIN = 129;   // in_features = D_IN+1
static constexpr int QP  = 80;    // padded q/k width (65 -> 80)
static constexpr int AMB = 65;    // ambient dim
static constexpr int XP  = 144;   // padded x row (129 -> 144)
static constexpr int NS  = 2;     // K-splits (1024 keys each)
static constexpr int PR  = 72;    // partial row pad (65 -> 72), 144 B
// Tiled K/V global layouts == LDS image (gload_lds linear-dest constraint):
static constexpr int KROW = 88;   // K tile row, u16 (176 B)
static constexpr int KTS  = 3072; // K tile size, u16 (6144 B = 6 x 1024B insts)
static constexpr int VROW = 40;   // V tile row, u16 (80 B)
static constexpr int VTS  = 4096; // V tile size, u16 (8192 B = 8 x 1024B insts)
static constexpr float LOG2E = 1.4426950408889634f;

#define DEV static __device__ __forceinline__

#if __has_builtin(__builtin_amdgcn_exp2f)
#define FEXP2 __builtin_amdgcn_exp2f
#else
#define FEXP2 exp2f
#endif

DEV u16 f2bf(float f) {
  union { __bf16 h; u16 u; } c;
  c.h = (__bf16)f;
  return c.u;
}
DEV float bf2f(u16 u) {
  union { float f; u32 uu; } c;
  c.uu = ((u32)u) << 16;
  return c.f;
}
DEV u32 cvtpk(float a, float b) {   // low16 = bf16(a), high16 = bf16(b)
  u32 r;
  asm("v_cvt_pk_bf16_f32 %0, %1, %2" : "=v"(r) : "v"(a), "v"(b));
  return r;
}
// v_permlane32_swap_b32 a, b: a[32:63] <-> b[0:31] (both registers updated).
// After swap(w0, w2): w0 = frag word holding low key-pair for ALL lanes,
// w2 = frag word holding high key-pair for ALL lanes (m214-v22 recipe).
DEV void swap32(u32& a, u32& b) {
  asm("v_permlane32_swap_b32 %0, %1" : "+v"(a), "+v"(b));
}
DEV void gload_lds16(const u16* g, u16* l) {   // 64 lanes x 16B -> 1024B linear LDS
  __builtin_amdgcn_global_load_lds(
      (const __attribute__((address_space(1))) unsigned int*)g,
      (__attribute__((address_space(3))) unsigned int*)l, 16, 0, 0);
}

// ---------------------------------------------------------------------------
// Prep: x (f32 [8192][129]) -> xb (bf16 [8192][144], zero-padded, 16B-aligned)
// ---------------------------------------------------------------------------
__global__ __launch_bounds__(256) void prep_k(const float* __restrict__ x,
                                              u16* __restrict__ xb) {
  const int t = blockIdx.x * 256 + threadIdx.x;   // 0 .. 8192*18-1
  const int row = t / 18, cg = t % 18;
  u16 tmp[8];
#pragma unroll
  for (int j = 0; j < 8; ++j) {
    const int c = cg * 8 + j;
    tmp[j] = (c < DIN) ? f2bf(x[(size_t)row * DIN + c]) : (u16)0;
  }
  u32x4 w;
  w[0] = (u32)tmp[0] | ((u32)tmp[1] << 16);
  w[1] = (u32)tmp[2] | ((u32)tmp[3] << 16);
  w[2] = (u32)tmp[4] | ((u32)tmp[5] << 16);
  w[3] = (u32)tmp[6] | ((u32)tmp[7] << 16);
  *((u32x4*)xb + t) = w;
}

// ---------------------------------------------------------------------------
// Projection: s = xb @ W[h] + b, lift (C_ATTN=1). Epilogue: scatter into a
// per-wave LDS tile (global-layout image), then coalesced b128 copy-out.
//   Qb:  [bh][n][80] bf16 = alpha' * [qs(64), q0], alpha' = 2*log2e/(scale+eps)
//   Ktl: [bh][tile][key][88] bf16 = [ks(64), -(k0-1), 0*15, junk*8]
//   Vtl: [bh][tile][dim][40] bf16 = col n&31; dims 0-63 vs, 64 v0; rows 65+ junk
// ---------------------------------------------------------------------------
__global__ __launch_bounds__(256) void proj_k(
    const u16* __restrict__ xb,
    const float* __restrict__ Wq, const float* __restrict__ Wk, const float* __restrict__ Wv,
    const float* __restrict__ bq, const float* __restrict__ bk, const float* __restrict__ bv,
    const float* __restrict__ scale_p,
    u16* __restrict__ Qb, u16* __restrict__ Ktl, u16* __restrict__ Vtl) {
  __shared__ u16 wt[64][152];                       // W^T: [d][k]
  __shared__ __align__(16) u16 tiles[4][2816];      // per-wave output tile image

  const int tid = threadIdx.x;
  const int wid = tid >> 6, l = tid & 63;
  const int z = blockIdx.y;            // 0..23
  const int T = z >> 3, h = z & 7;     // tensor (0=Q,1=K,2=V), head
  const float* W    = (T == 0 ? Wq : (T == 1 ? Wk : Wv)) + (size_t)h * DIN * 64;
  const float* bias = (T == 0 ? bq : (T == 1 ? bk : bv)) + h * 64;

  {
    const int d = tid & 63, kk = tid >> 6;
    for (int k = kk; k < XP; k += 4)
      wt[d][k] = (k < DIN) ? f2bf(W[(size_t)k * 64 + d]) : (u16)0;
  }
  __syncthreads();

  const int lo = l & 31, hi = l >> 5;
  const int row0 = (blockIdx.x * 4 + wid) * 32;
  const u16* xr = xb + (size_t)(row0 + lo) * XP;

  f32x16 acc0 = {}, acc1 = {};
#pragma unroll
  for (int s = 0; s < 9; ++s) {
    bf16x8 a  = *(const bf16x8*)&xr[16 * s + 8 * hi];
    bf16x8 b0 = *(const bf16x8*)&wt[lo][16 * s + 8 * hi];
    bf16x8 b1 = *(const bf16x8*)&wt[32 + lo][16 * s + 8 * hi];
    acc0 = __builtin_amdgcn_mfma_f32_32x32x16_bf16(a, b0, acc0, 0, 0, 0);
    acc1 = __builtin_amdgcn_mfma_f32_32x32x16_bf16(a, b1, acc1, 0, 0, 0);
  }
  const float b0v = bias[lo], b1v = bias[32 + lo];
  const float alpha = 2.0f * LOG2E / (scale_p[0] + 1e-7f);
  u16* tl = &tiles[wid][0];

#pragma unroll
  for (int r = 0; r < 16; ++r) {
    const float s0 = acc0[r] + b0v;
    const float s1 = acc1[r] + b1v;
    float part = s0 * s0 + s1 * s1;
#pragma unroll
    for (int m = 1; m < 32; m <<= 1) part += __shfl_xor(part, m);
    const float time = sqrtf(1.0f + part);     // 1/C_ATTN = 1
    const int dr = (r & 3) + 8 * (r >> 2) + 4 * hi;   // row within 32-row tile
    if (T == 0) {
      tl[dr * 80 + lo]      = f2bf(alpha * s0);
      tl[dr * 80 + 32 + lo] = f2bf(alpha * s1);
      if (lo == 0) tl[dr * 80 + 64] = f2bf(alpha * time);
      if (lo < 15) tl[dr * 80 + 65 + lo] = 0;
    } else if (T == 1) {
      tl[dr * 88 + lo]      = f2bf(s0);
      tl[dr * 88 + 32 + lo] = f2bf(s1);
      if (lo == 0) tl[dr * 88 + 64] = f2bf(-(time - 1.0f));  // centered time
      if (lo < 15) tl[dr * 88 + 65 + lo] = 0;
      if (lo < 8)  tl[dr * 88 + 80 + lo] = 0;   // keep copied bytes defined
    } else {
      tl[lo * 40 + dr]        = f2bf(s0);
      tl[(32 + lo) * 40 + dr] = f2bf(s1);
      if (lo == 0) tl[64 * 40 + dr] = f2bf(time);
    }
  }
  __syncthreads();

  // coalesced copy-out: 16B chunks
  const int b = row0 >> 11, n0 = row0 & 2047;
  const int bh = b * 8 + h;
  u16* gdst;
  int nch;
  if (T == 0) { gdst = Qb + ((size_t)bh * Nn + n0) * QP;                nch = 320; }
  else if (T == 1) { gdst = Ktl + (size_t)bh * 64 * KTS + (size_t)(n0 >> 5) * KTS; nch = 352; }
  else { gdst = Vtl + (size_t)bh * 64 * VTS + (size_t)(n0 >> 5) * VTS;  nch = 325; }
  for (int j = l; j < nch; j += 64)
    *(u32x4*)(gdst + j * 8) = *(const u32x4*)(tl + j * 8);
}

// ---------------------------------------------------------------------------
// attn staging: 14 gload_lds insts/tile split 4/4/3/3 across waves
// ---------------------------------------------------------------------------
DEV void stage_tile(const u16* kg, const u16* vg, u16* kl, u16* vl,
                    const int w, const int lane) {
  if (w < 2) {
#pragma unroll
    for (int i = 0; i < 3; ++i)
      gload_lds16(kg + (w * 3 + i) * 512 + lane * 8, kl + (w * 3 + i) * 512);
    gload_lds16(vg + w * 512 + lane * 8, vl + w * 512);
  } else {
#pragma unroll
    for (int i = 0; i < 3; ++i) {
      const int j = (w - 2) * 3 + 2 + i;     // 2..4 / 5..7
      gload_lds16(vg + j * 512 + lane * 8, vl + j * 512);
    }
  }
}

// T4 counted-vmcnt barrier: leave the newest tile's own loads (4 or 3) in
// flight, drain everything older + all lgkm.
DEV void waitbar(const int w) {
  if (w < 2)
    asm volatile("s_waitcnt vmcnt(4) lgkmcnt(0)\ns_barrier" ::: "memory");
  else
    asm volatile("s_waitcnt vmcnt(3) lgkmcnt(0)\ns_barrier" ::: "memory");
}

// exp2 + cvt_pk + permlane32_swap: scores (one 32-q half) -> P fragments.
// Pack own p into words; swap(w0,w2)/(w1,w3) redistributes across the
// lane^32 boundary so every lane holds contiguous key words (T12).
DEV void exp_pack(const f32x16 sc, bf16x8& fA, bf16x8& fB) {
  float p[16];
#pragma unroll
  for (int r = 0; r < 16; ++r) p[r] = FEXP2(sc[r]);
  u32 a0 = cvtpk(p[0], p[1]),  a1 = cvtpk(p[2], p[3]);
  u32 a2 = cvtpk(p[4], p[5]),  a3 = cvtpk(p[6], p[7]);
  u32 c0 = cvtpk(p[8], p[9]),  c1 = cvtpk(p[10], p[11]);
  u32 c2 = cvtpk(p[12], p[13]), c3 = cvtpk(p[14], p[15]);
  swap32(a0, a2);
  swap32(a1, a3);
  swap32(c0, c2);
  swap32(c1, c3);
  union { u32x4 u; bf16x8 b; } ca, cb;
  ca.u = (u32x4){a0, a1, a2, a3};
  cb.u = (u32x4){c0, c1, c2, c3};
  fA = ca.b;   // keys +0..15
  fB = cb.b;   // keys +16..31
}

// ---------------------------------------------------------------------------
// One 32-key tile for 64 q-rows: every K/V ds_read feeds 2 MFMA (half A: q
// cols qbase+0..31, half B: qbase+32..63). 22 MFMA / 11 b128 ds_reads.
// ---------------------------------------------------------------------------
DEV void compute_tile64(const u16* kl, const u16* vl, const int lo, const int hi,
                        const bf16x8 (&qA)[5], const bf16x8 (&qB)[5],
                        f32x16& a0, f32x16& a1, f32x16& a2,
                        f32x16& b0, f32x16& b1, f32x16& b2) {
  f32x16 sA = {}, sB = {};
#pragma unroll
  for (int s = 0; s < 5; ++s) {
    const bf16x8 kf = *(const bf16x8*)&kl[lo * KROW + 16 * s + 8 * hi];
    sA = __builtin_amdgcn_mfma_f32_32x32x16_bf16(kf, qA[s], sA, 0, 0, 0);
    sB = __builtin_amdgcn_mfma_f32_32x32x16_bf16(kf, qB[s], sB, 0, 0, 0);
  }
  bf16x8 fA0, fB0, fA1, fB1;
  exp_pack(sA, fA0, fB0);
  exp_pack(sB, fA1, fB1);
#pragma unroll
  for (int t = 0; t < 3; ++t) {
    const bf16x8 va = *(const bf16x8*)&vl[(32 * t + lo) * VROW + 8 * hi];
    const bf16x8 vb = *(const bf16x8*)&vl[(32 * t + lo) * VROW + 16 + 8 * hi];
    f32x16& oa = (t == 0 ? a0 : (t == 1 ? a1 : a2));
    f32x16& ob = (t == 0 ? b0 : (t == 1 ? b1 : b2));
    oa = __builtin_amdgcn_mfma_f32_32x32x16_bf16(va, fA0, oa, 0, 0, 0);
    oa = __builtin_amdgcn_mfma_f32_32x32x16_bf16(vb, fB0, oa, 0, 0, 0);
    ob = __builtin_amdgcn_mfma_f32_32x32x16_bf16(va, fA1, ob, 0, 0, 0);
    ob = __builtin_amdgcn_mfma_f32_32x32x16_bf16(vb, fB1, ob, 0, 0, 0);
  }
}

DEV void write_partial(u16* part, const int bh, const int sidx, const int q,
                       const int hi, const f32x16& o0, const f32x16& o1,
                       const f32x16& o2) {
  u16* po = part + ((size_t)((bh * NS + sidx) * Nn + q)) * PR;
#pragma unroll
  for (int t = 0; t < 4; ++t) {
    const u32 a0 = cvtpk(o0[4 * t], o0[4 * t + 1]);
    const u32 a1 = cvtpk(o0[4 * t + 2], o0[4 * t + 3]);
    const u32 b0 = cvtpk(o1[4 * t], o1[4 * t + 1]);
    const u32 b1 = cvtpk(o1[4 * t + 2], o1[4 * t + 3]);
    *(u32x2*)&po[8 * t + 4 * hi]      = (u32x2){a0, a1};
    *(u32x2*)&po[8 * t + 4 * hi + 32] = (u32x2){b0, b1};
  }
  if (hi == 0) po[64] = f2bf(o2[0]);
}

// ---------------------------------------------------------------------------
// Attention: 64 q/wave (2 fragment sets share all K/V reads), 3-buffer LDS,
// depth-2 prefetch, counted vmcnt. 4 waves/block = 256 q. XCD swizzle.
// Grid 512 = 32 bh x 2 splits x 8 qt = exactly 2 blocks/CU.
// ---------------------------------------------------------------------------
__global__ __launch_bounds__(256, 2) void attn_k(
    const u16* __restrict__ Qb, const u16* __restrict__ Ktl,
    const u16* __restrict__ Vtl, u16* __restrict__ part) {
  __shared__ u16 kls[3][KTS];
  __shared__ u16 vls[3][VTS];

  const int tid  = threadIdx.x;
  const int w    = tid >> 6, lane = tid & 63;
  const int lo   = lane & 31, hi = lane >> 5;

  // XCD-chunked swizzle (512 blocks, 8 XCDs, bijective): 4 whole bh per XCD
  const u32 bid = blockIdx.x;
  const u32 swz = (bid & 7) * 64 + (bid >> 3);
  const int bh   = swz >> 4;
  const int sidx = (swz >> 3) & 1;
  const int qt   = swz & 7;
  const int qbase = qt * 256 + w * 64;

  const u16* qrowA = Qb + ((size_t)bh * Nn + qbase + lo) * QP;
  const u16* qrowB = qrowA + 32 * QP;
  bf16x8 qA[5], qB[5];
#pragma unroll
  for (int s = 0; s < 5; ++s) {
    qA[s] = *(const bf16x8*)&qrowA[16 * s + 8 * hi];
    qB[s] = *(const bf16x8*)&qrowB[16 * s + 8 * hi];
  }

  f32x16 a0 = {}, a1 = {}, a2 = {};   // half A: O^T d rows, q cols qbase+lo
  f32x16 b0 = {}, b1 = {}, b2 = {};   // half B: q cols qbase+32+lo
  const u16* ktb = Ktl + (size_t)bh * 64 * KTS + (size_t)(sidx * 32) * KTS;
  const u16* vtb = Vtl + (size_t)bh * 64 * VTS + (size_t)(sidx * 32) * VTS;

  // prologue: prefetch tiles 0 and 1
  stage_tile(ktb, vtb, kls[0], vls[0], w, lane);
  stage_tile(ktb + KTS, vtb + VTS, kls[1], vls[1], w, lane);
  waitbar(w);   // tile 0 landed; tile 1 in flight

#pragma unroll 1
  for (int t = 0; t < 32; ++t) {
    const int pf = (t + 2 < 32) ? t + 2 : 31;   // clamp: redundant restage keeps vmcnt uniform
    stage_tile(ktb + (size_t)pf * KTS, vtb + (size_t)pf * VTS,
               kls[(t + 2) % 3], vls[(t + 2) % 3], w, lane);
    compute_tile64(kls[t % 3], vls[t % 3], lo, hi, qA, qB, a0, a1, a2, b0, b1, b2);
    waitbar(w);  // tile t+1 landed; tile t+2 in flight
  }

  write_partial(part, bh, sidx, qbase + lo,      hi, a0, a1, a2);
  write_partial(part, bh, sidx, qbase + 32 + lo, hi, b0, b1, b2);
}

// ---------------------------------------------------------------------------
// Finale (wave-cooperative): one wave per (b,n). Lane l -> (h = l>>3, chunk
// c = l&7). Combine 2 splits, per-head Lorentz normalize (shfl_xor 1,2,4),
// head-sum (shfl_xor 8,16,32), final normalize + re-lift.
// ---------------------------------------------------------------------------
__global__ __launch_bounds__(256) void finale_k(const u16* __restrict__ part,
                                                float* __restrict__ out) {
  const int tid = threadIdx.x;
  const int wv = tid >> 6, l = tid & 63;
  const int g = blockIdx.x * 4 + wv;       // 0..8191 = b*2048+n
  const int b = g >> 11, n = g & 2047;
  const int h = l >> 3, c = l & 7;

  const u16* rowp = part + ((size_t)((b * 8 + h) * NS) * Nn + n) * PR;
  float Oh[8];
#pragma unroll
  for (int j = 0; j < 8; ++j) Oh[j] = 0.f;
  float th = 0.f;
#pragma unroll
  for (int s = 0; s < NS; ++s) {
    const u16* rp = rowp + (size_t)s * Nn * PR;
    const u32x4 v = *(const u32x4*)&rp[8 * c];
#pragma unroll
    for (int i = 0; i < 4; ++i) {
      union { u32 u; float f; } a, bb;
      a.u  = v[i] << 16;
      bb.u = v[i] & 0xffff0000u;
      Oh[2 * i]     += a.f;
      Oh[2 * i + 1] += bb.f;
    }
    th += bf2f(rp[64]);
  }

  float sq = 0.f;
#pragma unroll
  for (int j = 0; j < 8; ++j) sq += Oh[j] * Oh[j];
  sq += __shfl_xor(sq, 1);
  sq += __shfl_xor(sq, 2);
  sq += __shfl_xor(sq, 4);
  const float invh = rsqrtf(fmaxf(th * th - sq, 1e-7f));

  float S[8];
#pragma unroll
  for (int j = 0; j < 8; ++j) S[j] = Oh[j] * invh;
  float T = th * invh;
#pragma unroll
  for (int m = 8; m <= 32; m <<= 1) {
#pragma unroll
    for (int j = 0; j < 8; ++j) S[j] += __shfl_xor(S[j], m);
    T += __shfl_xor(T, m);
  }

  float s2 = 0.f;
#pragma unroll
  for (int j = 0; j < 8; ++j) s2 += S[j] * S[j];
  s2 += __shfl_xor(s2, 1);
  s2 += __shfl_xor(s2, 2);
  s2 += __shfl_xor(s2, 4);
  const float inv = rsqrtf(fmaxf(T * T - s2, 1e-7f));
  const float ssp = s2 * inv * inv;        // ||spatial_out||^2

  float* o = out + (size_t)g * AMB;
  if (h == 0) {
#pragma unroll
    for (int j = 0; j < 8; ++j) o[1 + 8 * c + j] = S[j] * inv;
    if (l == 0) o[0] = sqrtf(1.0f + ssp);
  }
}

// ---------------------------------------------------------------------------
extern "C" void kernel_launch(void* const* d_in, const int* in_sizes, int n_in,
                              void* d_out, int out_size, void* d_ws, size_t ws_size,
                              hipStream_t stream) {
  (void)in_sizes; (void)n_in; (void)out_size; (void)ws_size;
  const float* x  = (const float*)d_in[0];
  const float* Wq = (const float*)d_in[1];
  const float* Wk = (const float*)d_in[2];
  const float* Wv = (const float*)d_in[3];
  const float* bq = (const float*)d_in[4];
  const float* bk = (const float*)d_in[5];
  const float* bv = (const float*)d_in[6];
  const float* sc = (const float*)d_in[7];
  // d_in[8] = attn_bias: uniform additive score offset -> softmax-invariant.

  char* ws = (char*)d_ws;
  u16*  Qb  = (u16*)(ws);                  // 10,485,760 B
  u16*  Ktl = (u16*)(ws + 10485760);       // 32*64*6144 = 12,582,912 B
  u16*  Vtl = (u16*)(ws + 23068672);       // 32*64*8192 = 16,777,216 B
  u16*  pb  = (u16*)(ws + 39845888);       // bf16 partials (NS=2): 18,874,368 B
  u16*  xb  = (u16*)(ws + 39845888);       // 2,359,296 B overlay, dead before attn_k
  float* out = (float*)d_out;

  hipLaunchKernelGGL(prep_k, dim3(576), dim3(256), 0, stream, x, xb);
  hipLaunchKernelGGL(proj_k, dim3(64, 24), dim3(256), 0, stream,
                     xb, Wq, Wk, Wv, bq, bk, bv, sc, Qb, Ktl, Vtl);
  hipLaunchKernelGGL(attn_k, dim3(512), dim3(256), 0, stream, Qb, Ktl, Vtl, pb);
  hipLaunchKernelGGL(finale_k, dim3(2048), dim3(256), 0, stream, pb, out);
}

// Round 13
// 93.231 us; speedup vs baseline: 1.2875x; 1.0961x over previous
//
#include <hip/hip_runtime.h>
#include <hip/hip_bf16.h>

typedef __bf16 bf16x8 __attribute__((ext_vector_type(8)));
typedef float f32x16 __attribute__((ext_vector_type(16)));
typedef unsigned int u32;
typedef unsigned short u16;
typedef u32 u32x2 __attribute__((ext_vector_type(2)));
typedef u32 u32x4 __attribute__((ext_vector_type(4)));

static constexpr int Nn  = 2048;
static constexpr int DIN = 129;   // in_features = D_IN+1
static constexpr int QP  = 80;    // padded q/k width (65 -> 80)
static constexpr int AMB = 65;    // ambient dim
static constexpr int XP  = 144;   // padded x row (129 -> 144); col 129 = 1.0 (bias)
static constexpr int NS  = 2;     // K-splits (1024 keys each)
static constexpr int PR  = 72;    // partial row pad (65 -> 72), 144 B
// Tiled K/V global layouts == LDS image (gload_lds linear-dest constraint):
static constexpr int KROW = 88;   // K tile row, u16 (176 B)
static constexpr int KTS  = 3072; // K tile size, u16 (6144 B = 6 x 1024B insts)
static constexpr int VROW = 40;   // V tile row, u16 (80 B)
static constexpr int VTS  = 4096; // V tile size, u16 (8192 B = 8 x 1024B insts)
static constexpr float LOG2E = 1.4426950408889634f;

#define DEV static __device__ __forceinline__

#if __has_builtin(__builtin_amdgcn_exp2f)
#define FEXP2 __builtin_amdgcn_exp2f
#else
#define FEXP2 exp2f
#endif

DEV u16 f2bf(float f) {
  union { __bf16 h; u16 u; } c;
  c.h = (__bf16)f;
  return c.u;
}
DEV float bf2f(u16 u) {
  union { float f; u32 uu; } c;
  c.uu = ((u32)u) << 16;
  return c.f;
}
DEV u32 cvtpk(float a, float b) {   // low16 = bf16(a), high16 = bf16(b)
  u32 r;
  asm("v_cvt_pk_bf16_f32 %0, %1, %2" : "=v"(r) : "v"(a), "v"(b));
  return r;
}
// v_permlane32_swap_b32 a, b: a[32:63] <-> b[0:31] (both registers updated).
DEV void swap32(u32& a, u32& b) {
  asm("v_permlane32_swap_b32 %0, %1" : "+v"(a), "+v"(b));
}
DEV void gload_lds16(const u16* g, u16* l) {   // 64 lanes x 16B -> 1024B linear LDS
  __builtin_amdgcn_global_load_lds(
      (const __attribute__((address_space(1))) unsigned int*)g,
      (__attribute__((address_space(3))) unsigned int*)l, 16, 0, 0);
}

// ---------------------------------------------------------------------------
// Prep: x (f32 [8192][129]) -> xb (bf16 [8192][144]); col 129 = 1.0 (bias
// augmentation: proj's wt row 129 holds the bias vector), cols 130..143 = 0.
// ---------------------------------------------------------------------------
__global__ __launch_bounds__(256) void prep_k(const float* __restrict__ x,
                                              u16* __restrict__ xb) {
  const int t = blockIdx.x * 256 + threadIdx.x;   // 0 .. 8192*18-1
  const int row = t / 18, cg = t % 18;
  u16 tmp[8];
#pragma unroll
  for (int j = 0; j < 8; ++j) {
    const int c = cg * 8 + j;
    tmp[j] = (c < DIN) ? f2bf(x[(size_t)row * DIN + c])
                       : (c == DIN ? f2bf(1.0f) : (u16)0);
  }
  u32x4 w;
  w[0] = (u32)tmp[0] | ((u32)tmp[1] << 16);
  w[1] = (u32)tmp[2] | ((u32)tmp[3] << 16);
  w[2] = (u32)tmp[4] | ((u32)tmp[5] << 16);
  w[3] = (u32)tmp[6] | ((u32)tmp[7] << 16);
  *((u32x4*)xb + t) = w;
}

// ---------------------------------------------------------------------------
// Projection, swapped-operand MFMA: D = mfma(W^T, x) -> D[d][row], so each
// lane owns one full output row (all d). Norm = in-lane sum of squares +
// one shfl_xor(32) (hi-halves hold complementary d's). Bias folded into the
// GEMM via augmented col 129. Epilogue: packed stores into per-wave LDS tile
// (global-layout image), then coalesced b128 copy-out.
//   Qb:  [bh][n][80] bf16 = alpha' * [qs(64), q0], alpha' = 2*log2e/(scale+eps)
//   Ktl: [bh][tile][key][88] bf16 = [ks(64), -(k0-1), 0*15, junk*8]
//   Vtl: [bh][tile][dim][40] bf16 = col n&31; dims 0-63 vs, 64 v0; rows 65+ junk
// ---------------------------------------------------------------------------
__global__ __launch_bounds__(256) void proj_k(
    const u16* __restrict__ xb,
    const float* __restrict__ Wq, const float* __restrict__ Wk, const float* __restrict__ Wv,
    const float* __restrict__ bq, const float* __restrict__ bk, const float* __restrict__ bv,
    const float* __restrict__ scale_p,
    u16* __restrict__ Qb, u16* __restrict__ Ktl, u16* __restrict__ Vtl) {
  __shared__ u16 wt[64][152];                       // W^T: [d][k], k 129 = bias[d]
  __shared__ __align__(16) u16 tiles[4][2816];      // per-wave output tile image

  const int tid = threadIdx.x;
  const int wid = tid >> 6, l = tid & 63;
  const int z = blockIdx.y;            // 0..23
  const int T = z >> 3, h = z & 7;     // tensor (0=Q,1=K,2=V), head
  const float* W    = (T == 0 ? Wq : (T == 1 ? Wk : Wv)) + (size_t)h * DIN * 64;
  const float* bias = (T == 0 ? bq : (T == 1 ? bk : bv)) + h * 64;

  {
    const int d = tid & 63, kk = tid >> 6;
    for (int k = kk; k < XP; k += 4)
      wt[d][k] = (k < DIN) ? f2bf(W[(size_t)k * 64 + d])
                           : (k == DIN ? f2bf(bias[d]) : (u16)0);
  }
  __syncthreads();

  const int lo = l & 31, hi = l >> 5;
  const int row0 = (blockIdx.x * 4 + wid) * 32;
  const u16* xr = xb + (size_t)(row0 + lo) * XP;

  // Swapped: A = W^T rows (m = d), B = x rows (n = row). D[d][row]:
  // lane (lo,hi) holds col row=lo, rows d = crow(r,hi) (acc0) / 32+crow (acc1).
  f32x16 acc0 = {}, acc1 = {};
#pragma unroll
  for (int s = 0; s < 9; ++s) {
    bf16x8 a  = *(const bf16x8*)&xr[16 * s + 8 * hi];
    bf16x8 b0 = *(const bf16x8*)&wt[lo][16 * s + 8 * hi];
    bf16x8 b1 = *(const bf16x8*)&wt[32 + lo][16 * s + 8 * hi];
    acc0 = __builtin_amdgcn_mfma_f32_32x32x16_bf16(b0, a, acc0, 0, 0, 0);
    acc1 = __builtin_amdgcn_mfma_f32_32x32x16_bf16(b1, a, acc1, 0, 0, 0);
  }
  const float alpha = 2.0f * LOG2E / (scale_p[0] + 1e-7f);

  // row norm: in-lane + one cross-half exchange
  float nrm = 0.f;
#pragma unroll
  for (int r = 0; r < 16; ++r) nrm += acc0[r] * acc0[r] + acc1[r] * acc1[r];
  nrm += __shfl_xor(nrm, 32);
  const float time = sqrtf(1.0f + nrm);     // 1/C_ATTN = 1

  u16* tl = &tiles[wid][0];
  // d for reg r: crow(r,hi) = (r&3) + 8*(r>>2) + 4*hi -> per g=r>>2, 4 contiguous.
  if (T == 0) {
#pragma unroll
    for (int g = 0; g < 4; ++g) {
      const u32 w0 = cvtpk(alpha * acc0[4 * g],     alpha * acc0[4 * g + 1]);
      const u32 w1 = cvtpk(alpha * acc0[4 * g + 2], alpha * acc0[4 * g + 3]);
      const u32 w2 = cvtpk(alpha * acc1[4 * g],     alpha * acc1[4 * g + 1]);
      const u32 w3 = cvtpk(alpha * acc1[4 * g + 2], alpha * acc1[4 * g + 3]);
      *(u32x2*)&tl[lo * 80 + 8 * g + 4 * hi]      = (u32x2){w0, w1};
      *(u32x2*)&tl[lo * 80 + 32 + 8 * g + 4 * hi] = (u32x2){w2, w3};
    }
    if (hi == 0) *(u32x4*)&tl[lo * 80 + 64] = (u32x4){(u32)f2bf(alpha * time), 0, 0, 0};
    else         *(u32x4*)&tl[lo * 80 + 72] = (u32x4){0, 0, 0, 0};
  } else if (T == 1) {
#pragma unroll
    for (int g = 0; g < 4; ++g) {
      const u32 w0 = cvtpk(acc0[4 * g],     acc0[4 * g + 1]);
      const u32 w1 = cvtpk(acc0[4 * g + 2], acc0[4 * g + 3]);
      const u32 w2 = cvtpk(acc1[4 * g],     acc1[4 * g + 1]);
      const u32 w3 = cvtpk(acc1[4 * g + 2], acc1[4 * g + 3]);
      *(u32x2*)&tl[lo * 88 + 8 * g + 4 * hi]      = (u32x2){w0, w1};
      *(u32x2*)&tl[lo * 88 + 32 + 8 * g + 4 * hi] = (u32x2){w2, w3};
    }
    if (hi == 0) *(u32x4*)&tl[lo * 88 + 64] = (u32x4){(u32)f2bf(-(time - 1.0f)), 0, 0, 0};
    else         *(u32x4*)&tl[lo * 88 + 72] = (u32x4){0, 0, 0, 0};
  } else {
#pragma unroll
    for (int r = 0; r < 16; ++r) {
      const int d = (r & 3) + 8 * (r >> 2) + 4 * hi;
      tl[d * 40 + lo]        = f2bf(acc0[r]);
      tl[(32 + d) * 40 + lo] = f2bf(acc1[r]);
    }
    if (hi == 0) tl[64 * 40 + lo] = f2bf(time);
  }
  __syncthreads();

  // coalesced copy-out: 16B chunks
  const int b = row0 >> 11, n0 = row0 & 2047;
  const int bh = b * 8 + h;
  u16* gdst;
  int nch;
  if (T == 0) { gdst = Qb + ((size_t)bh * Nn + n0) * QP;                nch = 320; }
  else if (T == 1) { gdst = Ktl + (size_t)bh * 64 * KTS + (size_t)(n0 >> 5) * KTS; nch = 352; }
  else { gdst = Vtl + (size_t)bh * 64 * VTS + (size_t)(n0 >> 5) * VTS;  nch = 325; }
  for (int j = l; j < nch; j += 64)
    *(u32x4*)(gdst + j * 8) = *(const u32x4*)(tl + j * 8);
}

// ---------------------------------------------------------------------------
// attn staging: one SUPER-tile (2 key-tiles) = 28 gload insts, exactly 7/wave
// ---------------------------------------------------------------------------
DEV void stage_super(const u16* kg, const u16* vg, u16* kl, u16* vl,
                     const int w, const int lane) {
  if (w == 0) {
#pragma unroll
    for (int i = 0; i < 6; ++i) gload_lds16(kg + i * 512 + lane * 8, kl + i * 512);
    gload_lds16(vg + lane * 8, vl);
  } else if (w == 1) {
#pragma unroll
    for (int i = 1; i < 8; ++i) gload_lds16(vg + i * 512 + lane * 8, vl + i * 512);
  } else if (w == 2) {
#pragma unroll
    for (int i = 6; i < 12; ++i) gload_lds16(kg + i * 512 + lane * 8, kl + i * 512);
    gload_lds16(vg + 8 * 512 + lane * 8, vl + 8 * 512);
  } else {
#pragma unroll
    for (int i = 9; i < 16; ++i) gload_lds16(vg + i * 512 + lane * 8, vl + i * 512);
  }
}

DEV void waitbar() {
  asm volatile("s_waitcnt vmcnt(0) lgkmcnt(0)\ns_barrier" ::: "memory");
}

// exp2 + cvt_pk + permlane32_swap: scores (one 32-q half) -> P fragments (T12)
DEV void exp_pack(const f32x16 sc, bf16x8& fA, bf16x8& fB) {
  float p[16];
#pragma unroll
  for (int r = 0; r < 16; ++r) p[r] = FEXP2(sc[r]);
  u32 a0 = cvtpk(p[0], p[1]),  a1 = cvtpk(p[2], p[3]);
  u32 a2 = cvtpk(p[4], p[5]),  a3 = cvtpk(p[6], p[7]);
  u32 c0 = cvtpk(p[8], p[9]),  c1 = cvtpk(p[10], p[11]);
  u32 c2 = cvtpk(p[12], p[13]), c3 = cvtpk(p[14], p[15]);
  swap32(a0, a2);
  swap32(a1, a3);
  swap32(c0, c2);
  swap32(c1, c3);
  union { u32x4 u; bf16x8 b; } ca, cb;
  ca.u = (u32x4){a0, a1, a2, a3};
  cb.u = (u32x4){c0, c1, c2, c3};
  fA = ca.b;   // keys +0..15
  fB = cb.b;   // keys +16..31
}

// ---------------------------------------------------------------------------
// One 32-key tile for 64 q-rows: every K/V ds_read feeds 2 MFMA.
// ---------------------------------------------------------------------------
DEV void compute_tile64(const u16* kl, const u16* vl, const int lo, const int hi,
                        const bf16x8 (&qA)[5], const bf16x8 (&qB)[5],
                        f32x16& a0, f32x16& a1, f32x16& a2,
                        f32x16& b0, f32x16& b1, f32x16& b2) {
  f32x16 sA = {}, sB = {};
#pragma unroll
  for (int s = 0; s < 5; ++s) {
    const bf16x8 kf = *(const bf16x8*)&kl[lo * KROW + 16 * s + 8 * hi];
    sA = __builtin_amdgcn_mfma_f32_32x32x16_bf16(kf, qA[s], sA, 0, 0, 0);
    sB = __builtin_amdgcn_mfma_f32_32x32x16_bf16(kf, qB[s], sB, 0, 0, 0);
  }
  bf16x8 fA0, fB0, fA1, fB1;
  exp_pack(sA, fA0, fB0);
  exp_pack(sB, fA1, fB1);
#pragma unroll
  for (int t = 0; t < 3; ++t) {
    const bf16x8 va = *(const bf16x8*)&vl[(32 * t + lo) * VROW + 8 * hi];
    const bf16x8 vb = *(const bf16x8*)&vl[(32 * t + lo) * VROW + 16 + 8 * hi];
    f32x16& oa = (t == 0 ? a0 : (t == 1 ? a1 : a2));
    f32x16& ob = (t == 0 ? b0 : (t == 1 ? b1 : b2));
    oa = __builtin_amdgcn_mfma_f32_32x32x16_bf16(va, fA0, oa, 0, 0, 0);
    oa = __builtin_amdgcn_mfma_f32_32x32x16_bf16(vb, fB0, oa, 0, 0, 0);
    ob = __builtin_amdgcn_mfma_f32_32x32x16_bf16(va, fA1, ob, 0, 0, 0);
    ob = __builtin_amdgcn_mfma_f32_32x32x16_bf16(vb, fB1, ob, 0, 0, 0);
  }
}

DEV void write_partial(u16* part, const int bh, const int sidx, const int q,
                       const int hi, const f32x16& o0, const f32x16& o1,
                       const f32x16& o2) {
  u16* po = part + ((size_t)((bh * NS + sidx) * Nn + q)) * PR;
#pragma unroll
  for (int t = 0; t < 4; ++t) {
    const u32 a0 = cvtpk(o0[4 * t], o0[4 * t + 1]);
    const u32 a1 = cvtpk(o0[4 * t + 2], o0[4 * t + 3]);
    const u32 b0 = cvtpk(o1[4 * t], o1[4 * t + 1]);
    const u32 b1 = cvtpk(o1[4 * t + 2], o1[4 * t + 3]);
    *(u32x2*)&po[8 * t + 4 * hi]      = (u32x2){a0, a1};
    *(u32x2*)&po[8 * t + 4 * hi + 32] = (u32x2){b0, b1};
  }
  if (hi == 0) po[64] = f2bf(o2[0]);
}

// ---------------------------------------------------------------------------
// Attention: 64 q/wave, 64-key SUPER-tiles (2 tiles per sync interval),
// 2 super-buffers, depth-1 prefetch, one vmcnt(0)+barrier per super.
// 4 waves/block = 256 q. XCD swizzle. Grid 512 = 32 bh x 2 splits x 8 qt.
// ---------------------------------------------------------------------------
__global__ __launch_bounds__(256, 2) void attn_k(
    const u16* __restrict__ Qb, const u16* __restrict__ Ktl,
    const u16* __restrict__ Vtl, u16* __restrict__ part) {
  __shared__ u16 kls[2][2 * KTS];   // 2 super-buffers x 2 K tiles
  __shared__ u16 vls[2][2 * VTS];   // 2 super-buffers x 2 V tiles

  const int tid  = threadIdx.x;
  const int w    = tid >> 6, lane = tid & 63;
  const int lo   = lane & 31, hi = lane >> 5;

  // XCD-chunked swizzle (512 blocks, 8 XCDs, bijective): 4 whole bh per XCD
  const u32 bid = blockIdx.x;
  const u32 swz = (bid & 7) * 64 + (bid >> 3);
  const int bh   = swz >> 4;
  const int sidx = (swz >> 3) & 1;
  const int qt   = swz & 7;
  const int qbase = qt * 256 + w * 64;

  const u16* qrowA = Qb + ((size_t)bh * Nn + qbase + lo) * QP;
  const u16* qrowB = qrowA + 32 * QP;
  bf16x8 qA[5], qB[5];
#pragma unroll
  for (int s = 0; s < 5; ++s) {
    qA[s] = *(const bf16x8*)&qrowA[16 * s + 8 * hi];
    qB[s] = *(const bf16x8*)&qrowB[16 * s + 8 * hi];
  }

  f32x16 a0 = {}, a1 = {}, a2 = {};   // half A: O^T d rows, q cols qbase+lo
  f32x16 b0 = {}, b1 = {}, b2 = {};   // half B: q cols qbase+32+lo
  const u16* ktb = Ktl + (size_t)bh * 64 * KTS + (size_t)(sidx * 32) * KTS;
  const u16* vtb = Vtl + (size_t)bh * 64 * VTS + (size_t)(sidx * 32) * VTS;

  // prologue: stage super 0 -> buf0
  stage_super(ktb, vtb, kls[0], vls[0], w, lane);
  waitbar();

#pragma unroll 1
  for (int s = 0; s < 16; ++s) {
    const int pf = (s + 1 < 16) ? s + 1 : 15;   // clamp: redundant tail restage
    stage_super(ktb + (size_t)pf * 2 * KTS, vtb + (size_t)pf * 2 * VTS,
                kls[(s + 1) & 1], vls[(s + 1) & 1], w, lane);
    compute_tile64(kls[s & 1],       vls[s & 1],       lo, hi, qA, qB, a0, a1, a2, b0, b1, b2);
    compute_tile64(kls[s & 1] + KTS, vls[s & 1] + VTS, lo, hi, qA, qB, a0, a1, a2, b0, b1, b2);
    waitbar();   // drains the depth-1 prefetch; compute (~2 tiles) covered it
  }

  write_partial(part, bh, sidx, qbase + lo,      hi, a0, a1, a2);
  write_partial(part, bh, sidx, qbase + 32 + lo, hi, b0, b1, b2);
}

// ---------------------------------------------------------------------------
// Finale (wave-cooperative): one wave per (b,n). Lane l -> (h = l>>3, chunk
// c = l&7). Combine 2 splits, per-head Lorentz normalize (shfl_xor 1,2,4),
// head-sum (shfl_xor 8,16,32), final normalize + re-lift.
// ---------------------------------------------------------------------------
__global__ __launch_bounds__(256) void finale_k(const u16* __restrict__ part,
                                                float* __restrict__ out) {
  const int tid = threadIdx.x;
  const int wv = tid >> 6, l = tid & 63;
  const int g = blockIdx.x * 4 + wv;       // 0..8191 = b*2048+n
  const int b = g >> 11, n = g & 2047;
  const int h = l >> 3, c = l & 7;

  const u16* rowp = part + ((size_t)((b * 8 + h) * NS) * Nn + n) * PR;
  float Oh[8];
#pragma unroll
  for (int j = 0; j < 8; ++j) Oh[j] = 0.f;
  float th = 0.f;
#pragma unroll
  for (int s = 0; s < NS; ++s) {
    const u16* rp = rowp + (size_t)s * Nn * PR;
    const u32x4 v = *(const u32x4*)&rp[8 * c];
#pragma unroll
    for (int i = 0; i < 4; ++i) {
      union { u32 u; float f; } a, bb;
      a.u  = v[i] << 16;
      bb.u = v[i] & 0xffff0000u;
      Oh[2 * i]     += a.f;
      Oh[2 * i + 1] += bb.f;
    }
    th += bf2f(rp[64]);
  }

  float sq = 0.f;
#pragma unroll
  for (int j = 0; j < 8; ++j) sq += Oh[j] * Oh[j];
  sq += __shfl_xor(sq, 1);
  sq += __shfl_xor(sq, 2);
  sq += __shfl_xor(sq, 4);
  const float invh = rsqrtf(fmaxf(th * th - sq, 1e-7f));

  float S[8];
#pragma unroll
  for (int j = 0; j < 8; ++j) S[j] = Oh[j] * invh;
  float T = th * invh;
#pragma unroll
  for (int m = 8; m <= 32; m <<= 1) {
#pragma unroll
    for (int j = 0; j < 8; ++j) S[j] += __shfl_xor(S[j], m);
    T += __shfl_xor(T, m);
  }

  float s2 = 0.f;
#pragma unroll
  for (int j = 0; j < 8; ++j) s2 += S[j] * S[j];
  s2 += __shfl_xor(s2, 1);
  s2 += __shfl_xor(s2, 2);
  s2 += __shfl_xor(s2, 4);
  const float inv = rsqrtf(fmaxf(T * T - s2, 1e-7f));
  const float ssp = s2 * inv * inv;        // ||spatial_out||^2

  float* o = out + (size_t)g * AMB;
  if (h == 0) {
#pragma unroll
    for (int j = 0; j < 8; ++j) o[1 + 8 * c + j] = S[j] * inv;
    if (l == 0) o[0] = sqrtf(1.0f + ssp);
  }
}

// ---------------------------------------------------------------------------
extern "C" void kernel_launch(void* const* d_in, const int* in_sizes, int n_in,
                              void* d_out, int out_size, void* d_ws, size_t ws_size,
                              hipStream_t stream) {
  (void)in_sizes; (void)n_in; (void)out_size; (void)ws_size;
  const float* x  = (const float*)d_in[0];
  const float* Wq = (const float*)d_in[1];
  const float* Wk = (const float*)d_in[2];
  const float* Wv = (const float*)d_in[3];
  const float* bq = (const float*)d_in[4];
  const float* bk = (const float*)d_in[5];
  const float* bv = (const float*)d_in[6];
  const float* sc = (const float*)d_in[7];
  // d_in[8] = attn_bias: uniform additive score offset -> softmax-invariant.

  char* ws = (char*)d_ws;
  u16*  Qb  = (u16*)(ws);                  // 10,485,760 B
  u16*  Ktl = (u16*)(ws + 10485760);       // 32*64*6144 = 12,582,912 B
  u16*  Vtl = (u16*)(ws + 23068672);       // 32*64*8192 = 16,777,216 B
  u16*  pb  = (u16*)(ws + 39845888);       // bf16 partials (NS=2): 18,874,368 B
  u16*  xb  = (u16*)(ws + 39845888);       // 2,359,296 B overlay, dead before attn_k
  float* out = (float*)d_out;

  hipLaunchKernelGGL(prep_k, dim3(576), dim3(256), 0, stream, x, xb);
  hipLaunchKernelGGL(proj_k, dim3(64, 24), dim3(256), 0, stream,
                     xb, Wq, Wk, Wv, bq, bk, bv, sc, Qb, Ktl, Vtl);
  hipLaunchKernelGGL(attn_k, dim3(512), dim3(256), 0, stream, Qb, Ktl, Vtl, pb);
  hipLaunchKernelGGL(finale_k, dim3(2048), dim3(256), 0, stream, pb, out);
}

// Round 14
// 84.294 us; speedup vs baseline: 1.4240x; 1.1060x over previous
//
#include <hip/hip_runtime.h>
#include <hip/hip_bf16.h>

typedef __bf16 bf16x8 __attribute__((ext_vector_type(8)));
typedef float f32x16 __attribute__((ext_vector_type(16)));
typedef unsigned int u32;
typedef unsigned short u16;
typedef u32 u32x2 __attribute__((ext_vector_type(2)));
typedef u32 u32x4 __attribute__((ext_vector_type(4)));

static constexpr int Nn  = 2048;
static constexpr int DIN = 129;   // in_features = D_IN+1
static constexpr int QP  = 80;    // padded q/k width (65 -> 80)
static constexpr int AMB = 65;    // ambient dim
static constexpr int XP  = 144;   // padded x row (129 -> 144); col 129 = 1.0 (bias)
static constexpr int NS  = 2;     // K-splits (1024 keys each)
static constexpr int PR  = 72;    // partial row pad (65 -> 72), 144 B
// Tiled K/V global layouts == LDS image (gload_lds linear-dest constraint):
static constexpr int KROW = 88;   // K tile row, u16 (176 B)
static constexpr int KTS  = 3072; // K tile size, u16 (6144 B = 6 x 1024B insts)
static constexpr int VROW = 40;   // V tile row, u16 (80 B)
static constexpr int VTS  = 4096; // V tile size, u16 (8192 B = 8 x 1024B insts)
static constexpr float LOG2E = 1.4426950408889634f;

#define DEV static __device__ __forceinline__

#if __has_builtin(__builtin_amdgcn_exp2f)
#define FEXP2 __builtin_amdgcn_exp2f
#else
#define FEXP2 exp2f
#endif

DEV u16 f2bf(float f) {
  union { __bf16 h; u16 u; } c;
  c.h = (__bf16)f;
  return c.u;
}
DEV float bf2f(u16 u) {
  union { float f; u32 uu; } c;
  c.uu = ((u32)u) << 16;
  return c.f;
}
DEV u32 cvtpk(float a, float b) {   // low16 = bf16(a), high16 = bf16(b)
  u32 r;
  asm("v_cvt_pk_bf16_f32 %0, %1, %2" : "=v"(r) : "v"(a), "v"(b));
  return r;
}
// v_permlane32_swap_b32 a, b: a[32:63] <-> b[0:31] (both registers updated).
DEV void swap32(u32& a, u32& b) {
  asm("v_permlane32_swap_b32 %0, %1" : "+v"(a), "+v"(b));
}
DEV void gload_lds16(const u16* g, u16* l) {   // 64 lanes x 16B -> 1024B linear LDS
  __builtin_amdgcn_global_load_lds(
      (const __attribute__((address_space(1))) unsigned int*)g,
      (__attribute__((address_space(3))) unsigned int*)l, 16, 0, 0);
}

// ---------------------------------------------------------------------------
// Prep: x (f32 [8192][129]) -> xb (bf16 [8192][144]); col 129 = 1.0 (bias
// augmentation: proj's wt row 129 holds the bias vector), cols 130..143 = 0.
// ---------------------------------------------------------------------------
__global__ __launch_bounds__(256) void prep_k(const float* __restrict__ x,
                                              u16* __restrict__ xb) {
  const int t = blockIdx.x * 256 + threadIdx.x;   // 0 .. 8192*18-1
  const int row = t / 18, cg = t % 18;
  u16 tmp[8];
#pragma unroll
  for (int j = 0; j < 8; ++j) {
    const int c = cg * 8 + j;
    tmp[j] = (c < DIN) ? f2bf(x[(size_t)row * DIN + c])
                       : (c == DIN ? f2bf(1.0f) : (u16)0);
  }
  u32x4 w;
  w[0] = (u32)tmp[0] | ((u32)tmp[1] << 16);
  w[1] = (u32)tmp[2] | ((u32)tmp[3] << 16);
  w[2] = (u32)tmp[4] | ((u32)tmp[5] << 16);
  w[3] = (u32)tmp[6] | ((u32)tmp[7] << 16);
  *((u32x4*)xb + t) = w;
}

// ---------------------------------------------------------------------------
// Projection, swapped-operand MFMA: D = mfma(W^T, x) -> D[d][row]; each lane
// owns one full output row. Norm = in-lane sum of squares + one shfl_xor(32).
// Bias folded via augmented col 129. W staged ONCE per block, reused for 2
// row-tiles per wave (W traffic halved vs 1-tile). Per-wave LDS tile image,
// coalesced b128 copy-out, no block barrier in the tile loop (tile private).
//   Qb:  [bh][n][80] bf16 = alpha' * [qs(64), q0], alpha' = 2*log2e/(scale+eps)
//   Ktl: [bh][tile][key][88] bf16 = [ks(64), -(k0-1), 0*15, junk*8]
//   Vtl: [bh][tile][dim][40] bf16 = col n&31; dims 0-63 vs, 64 v0; rows 65+ junk
// ---------------------------------------------------------------------------
__global__ __launch_bounds__(256) void proj_k(
    const u16* __restrict__ xb,
    const float* __restrict__ Wq, const float* __restrict__ Wk, const float* __restrict__ Wv,
    const float* __restrict__ bq, const float* __restrict__ bk, const float* __restrict__ bv,
    const float* __restrict__ scale_p,
    u16* __restrict__ Qb, u16* __restrict__ Ktl, u16* __restrict__ Vtl) {
  __shared__ u16 wt[64][152];                       // W^T: [d][k], k 129 = bias[d]
  __shared__ __align__(16) u16 tiles[4][2816];      // per-wave output tile image

  const int tid = threadIdx.x;
  const int wid = tid >> 6, l = tid & 63;
  const int z = blockIdx.y;            // 0..23
  const int T = z >> 3, h = z & 7;     // tensor (0=Q,1=K,2=V), head
  const float* W    = (T == 0 ? Wq : (T == 1 ? Wk : Wv)) + (size_t)h * DIN * 64;
  const float* bias = (T == 0 ? bq : (T == 1 ? bk : bv)) + h * 64;

  {
    const int d = tid & 63, kk = tid >> 6;
    for (int k = kk; k < XP; k += 4)
      wt[d][k] = (k < DIN) ? f2bf(W[(size_t)k * 64 + d])
                           : (k == DIN ? f2bf(bias[d]) : (u16)0);
  }
  __syncthreads();

  const int lo = l & 31, hi = l >> 5;
  const float alpha = 2.0f * LOG2E / (scale_p[0] + 1e-7f);
  u16* tl = &tiles[wid][0];

#pragma unroll 1
  for (int rt = 0; rt < 2; ++rt) {
    const int row0 = (blockIdx.x * 8 + wid * 2 + rt) * 32;
    const u16* xr = xb + (size_t)(row0 + lo) * XP;

    // Swapped: A = W^T rows (m = d), B = x rows (n = row). D[d][row]:
    // lane (lo,hi) holds col row=lo, rows d = crow(r,hi) (acc0) / 32+crow (acc1).
    f32x16 acc0 = {}, acc1 = {};
#pragma unroll
    for (int s = 0; s < 9; ++s) {
      bf16x8 a  = *(const bf16x8*)&xr[16 * s + 8 * hi];
      bf16x8 b0 = *(const bf16x8*)&wt[lo][16 * s + 8 * hi];
      bf16x8 b1 = *(const bf16x8*)&wt[32 + lo][16 * s + 8 * hi];
      acc0 = __builtin_amdgcn_mfma_f32_32x32x16_bf16(b0, a, acc0, 0, 0, 0);
      acc1 = __builtin_amdgcn_mfma_f32_32x32x16_bf16(b1, a, acc1, 0, 0, 0);
    }

    // row norm: in-lane + one cross-half exchange
    float nrm = 0.f;
#pragma unroll
    for (int r = 0; r < 16; ++r) nrm += acc0[r] * acc0[r] + acc1[r] * acc1[r];
    nrm += __shfl_xor(nrm, 32);
    const float time = sqrtf(1.0f + nrm);     // 1/C_ATTN = 1

    // d for reg r: crow(r,hi) = (r&3) + 8*(r>>2) + 4*hi -> per g=r>>2, 4 contiguous.
    if (T == 0) {
#pragma unroll
      for (int g = 0; g < 4; ++g) {
        const u32 w0 = cvtpk(alpha * acc0[4 * g],     alpha * acc0[4 * g + 1]);
        const u32 w1 = cvtpk(alpha * acc0[4 * g + 2], alpha * acc0[4 * g + 3]);
        const u32 w2 = cvtpk(alpha * acc1[4 * g],     alpha * acc1[4 * g + 1]);
        const u32 w3 = cvtpk(alpha * acc1[4 * g + 2], alpha * acc1[4 * g + 3]);
        *(u32x2*)&tl[lo * 80 + 8 * g + 4 * hi]      = (u32x2){w0, w1};
        *(u32x2*)&tl[lo * 80 + 32 + 8 * g + 4 * hi] = (u32x2){w2, w3};
      }
      if (hi == 0) *(u32x4*)&tl[lo * 80 + 64] = (u32x4){(u32)f2bf(alpha * time), 0, 0, 0};
      else         *(u32x4*)&tl[lo * 80 + 72] = (u32x4){0, 0, 0, 0};
    } else if (T == 1) {
#pragma unroll
      for (int g = 0; g < 4; ++g) {
        const u32 w0 = cvtpk(acc0[4 * g],     acc0[4 * g + 1]);
        const u32 w1 = cvtpk(acc0[4 * g + 2], acc0[4 * g + 3]);
        const u32 w2 = cvtpk(acc1[4 * g],     acc1[4 * g + 1]);
        const u32 w3 = cvtpk(acc1[4 * g + 2], acc1[4 * g + 3]);
        *(u32x2*)&tl[lo * 88 + 8 * g + 4 * hi]      = (u32x2){w0, w1};
        *(u32x2*)&tl[lo * 88 + 32 + 8 * g + 4 * hi] = (u32x2){w2, w3};
      }
      if (hi == 0) *(u32x4*)&tl[lo * 88 + 64] = (u32x4){(u32)f2bf(-(time - 1.0f)), 0, 0, 0};
      else         *(u32x4*)&tl[lo * 88 + 72] = (u32x4){0, 0, 0, 0};
    } else {
#pragma unroll
      for (int r = 0; r < 16; ++r) {
        const int d = (r & 3) + 8 * (r >> 2) + 4 * hi;
        tl[d * 40 + lo]        = f2bf(acc0[r]);
        tl[(32 + d) * 40 + lo] = f2bf(acc1[r]);
      }
      if (hi == 0) tl[64 * 40 + lo] = f2bf(time);
    }
    // per-wave private tile: same-wave DS ordering makes a barrier unnecessary

    // coalesced copy-out: 16B chunks
    const int b = row0 >> 11, n0 = row0 & 2047;
    const int bh = b * 8 + h;
    u16* gdst;
    int nch;
    if (T == 0) { gdst = Qb + ((size_t)bh * Nn + n0) * QP;                nch = 320; }
    else if (T == 1) { gdst = Ktl + (size_t)bh * 64 * KTS + (size_t)(n0 >> 5) * KTS; nch = 352; }
    else { gdst = Vtl + (size_t)bh * 64 * VTS + (size_t)(n0 >> 5) * VTS;  nch = 325; }
    for (int j = l; j < nch; j += 64)
      *(u32x4*)(gdst + j * 8) = *(const u32x4*)(tl + j * 8);
  }
}

// ---------------------------------------------------------------------------
// attn staging: one SUPER-tile (2 key-tiles) = 28 gload insts, exactly 7/wave
// ---------------------------------------------------------------------------
DEV void stage_super(const u16* kg, const u16* vg, u16* kl, u16* vl,
                     const int w, const int lane) {
  if (w == 0) {
#pragma unroll
    for (int i = 0; i < 6; ++i) gload_lds16(kg + i * 512 + lane * 8, kl + i * 512);
    gload_lds16(vg + lane * 8, vl);
  } else if (w == 1) {
#pragma unroll
    for (int i = 1; i < 8; ++i) gload_lds16(vg + i * 512 + lane * 8, vl + i * 512);
  } else if (w == 2) {
#pragma unroll
    for (int i = 6; i < 12; ++i) gload_lds16(kg + i * 512 + lane * 8, kl + i * 512);
    gload_lds16(vg + 8 * 512 + lane * 8, vl + 8 * 512);
  } else {
#pragma unroll
    for (int i = 9; i < 16; ++i) gload_lds16(vg + i * 512 + lane * 8, vl + i * 512);
  }
}

DEV void waitbar() {
  asm volatile("s_waitcnt vmcnt(0) lgkmcnt(0)\ns_barrier" ::: "memory");
}

// exp2 + cvt_pk + permlane32_swap: scores (one 32-q half) -> P fragments (T12)
DEV void exp_pack(const f32x16 sc, bf16x8& fA, bf16x8& fB) {
  float p[16];
#pragma unroll
  for (int r = 0; r < 16; ++r) p[r] = FEXP2(sc[r]);
  u32 a0 = cvtpk(p[0], p[1]),  a1 = cvtpk(p[2], p[3]);
  u32 a2 = cvtpk(p[4], p[5]),  a3 = cvtpk(p[6], p[7]);
  u32 c0 = cvtpk(p[8], p[9]),  c1 = cvtpk(p[10], p[11]);
  u32 c2 = cvtpk(p[12], p[13]), c3 = cvtpk(p[14], p[15]);
  swap32(a0, a2);
  swap32(a1, a3);
  swap32(c0, c2);
  swap32(c1, c3);
  union { u32x4 u; bf16x8 b; } ca, cb;
  ca.u = (u32x4){a0, a1, a2, a3};
  cb.u = (u32x4){c0, c1, c2, c3};
  fA = ca.b;   // keys +0..15
  fB = cb.b;   // keys +16..31
}

// ---------------------------------------------------------------------------
// One 32-key tile for 64 q-rows: every K/V ds_read feeds 2 MFMA. s_setprio
// around MFMA clusters (T5: phase-diverse 2-block interleave -> scheduler
// can favor the MFMA-entering wave).
// ---------------------------------------------------------------------------
DEV void compute_tile64(const u16* kl, const u16* vl, const int lo, const int hi,
                        const bf16x8 (&qA)[5], const bf16x8 (&qB)[5],
                        f32x16& a0, f32x16& a1, f32x16& a2,
                        f32x16& b0, f32x16& b1, f32x16& b2) {
  f32x16 sA = {}, sB = {};
  __builtin_amdgcn_s_setprio(1);
#pragma unroll
  for (int s = 0; s < 5; ++s) {
    const bf16x8 kf = *(const bf16x8*)&kl[lo * KROW + 16 * s + 8 * hi];
    sA = __builtin_amdgcn_mfma_f32_32x32x16_bf16(kf, qA[s], sA, 0, 0, 0);
    sB = __builtin_amdgcn_mfma_f32_32x32x16_bf16(kf, qB[s], sB, 0, 0, 0);
  }
  __builtin_amdgcn_s_setprio(0);
  bf16x8 fA0, fB0, fA1, fB1;
  exp_pack(sA, fA0, fB0);
  exp_pack(sB, fA1, fB1);
  __builtin_amdgcn_s_setprio(1);
#pragma unroll
  for (int t = 0; t < 3; ++t) {
    const bf16x8 va = *(const bf16x8*)&vl[(32 * t + lo) * VROW + 8 * hi];
    const bf16x8 vb = *(const bf16x8*)&vl[(32 * t + lo) * VROW + 16 + 8 * hi];
    f32x16& oa = (t == 0 ? a0 : (t == 1 ? a1 : a2));
    f32x16& ob = (t == 0 ? b0 : (t == 1 ? b1 : b2));
    oa = __builtin_amdgcn_mfma_f32_32x32x16_bf16(va, fA0, oa, 0, 0, 0);
    oa = __builtin_amdgcn_mfma_f32_32x32x16_bf16(vb, fB0, oa, 0, 0, 0);
    ob = __builtin_amdgcn_mfma_f32_32x32x16_bf16(va, fA1, ob, 0, 0, 0);
    ob = __builtin_amdgcn_mfma_f32_32x32x16_bf16(vb, fB1, ob, 0, 0, 0);
  }
  __builtin_amdgcn_s_setprio(0);
}

DEV void write_partial(u16* part, const int bh, const int sidx, const int q,
                       const int hi, const f32x16& o0, const f32x16& o1,
                       const f32x16& o2) {
  u16* po = part + ((size_t)((bh * NS + sidx) * Nn + q)) * PR;
#pragma unroll
  for (int t = 0; t < 4; ++t) {
    const u32 a0 = cvtpk(o0[4 * t], o0[4 * t + 1]);
    const u32 a1 = cvtpk(o0[4 * t + 2], o0[4 * t + 3]);
    const u32 b0 = cvtpk(o1[4 * t], o1[4 * t + 1]);
    const u32 b1 = cvtpk(o1[4 * t + 2], o1[4 * t + 3]);
    *(u32x2*)&po[8 * t + 4 * hi]      = (u32x2){a0, a1};
    *(u32x2*)&po[8 * t + 4 * hi + 32] = (u32x2){b0, b1};
  }
  if (hi == 0) po[64] = f2bf(o2[0]);
}

// ---------------------------------------------------------------------------
// Attention: 64 q/wave, 64-key SUPER-tiles (2 tiles per sync interval),
// 2 super-buffers, depth-1 prefetch, one vmcnt(0)+barrier per super.
// 4 waves/block = 256 q. XCD swizzle. Grid 512 = 32 bh x 2 splits x 8 qt.
// ---------------------------------------------------------------------------
__global__ __launch_bounds__(256, 2) void attn_k(
    const u16* __restrict__ Qb, const u16* __restrict__ Ktl,
    const u16* __restrict__ Vtl, u16* __restrict__ part) {
  __shared__ u16 kls[2][2 * KTS];   // 2 super-buffers x 2 K tiles
  __shared__ u16 vls[2][2 * VTS];   // 2 super-buffers x 2 V tiles

  const int tid  = threadIdx.x;
  const int w    = tid >> 6, lane = tid & 63;
  const int lo   = lane & 31, hi = lane >> 5;

  // XCD-chunked swizzle (512 blocks, 8 XCDs, bijective): 4 whole bh per XCD
  const u32 bid = blockIdx.x;
  const u32 swz = (bid & 7) * 64 + (bid >> 3);
  const int bh   = swz >> 4;
  const int sidx = (swz >> 3) & 1;
  const int qt   = swz & 7;
  const int qbase = qt * 256 + w * 64;

  const u16* qrowA = Qb + ((size_t)bh * Nn + qbase + lo) * QP;
  const u16* qrowB = qrowA + 32 * QP;
  bf16x8 qA[5], qB[5];
#pragma unroll
  for (int s = 0; s < 5; ++s) {
    qA[s] = *(const bf16x8*)&qrowA[16 * s + 8 * hi];
    qB[s] = *(const bf16x8*)&qrowB[16 * s + 8 * hi];
  }

  f32x16 a0 = {}, a1 = {}, a2 = {};   // half A: O^T d rows, q cols qbase+lo
  f32x16 b0 = {}, b1 = {}, b2 = {};   // half B: q cols qbase+32+lo
  const u16* ktb = Ktl + (size_t)bh * 64 * KTS + (size_t)(sidx * 32) * KTS;
  const u16* vtb = Vtl + (size_t)bh * 64 * VTS + (size_t)(sidx * 32) * VTS;

  // prologue: stage super 0 -> buf0
  stage_super(ktb, vtb, kls[0], vls[0], w, lane);
  waitbar();

#pragma unroll 1
  for (int s = 0; s < 16; ++s) {
    const int pf = (s + 1 < 16) ? s + 1 : 15;   // clamp: redundant tail restage
    stage_super(ktb + (size_t)pf * 2 * KTS, vtb + (size_t)pf * 2 * VTS,
                kls[(s + 1) & 1], vls[(s + 1) & 1], w, lane);
    compute_tile64(kls[s & 1],       vls[s & 1],       lo, hi, qA, qB, a0, a1, a2, b0, b1, b2);
    compute_tile64(kls[s & 1] + KTS, vls[s & 1] + VTS, lo, hi, qA, qB, a0, a1, a2, b0, b1, b2);
    waitbar();   // drains the depth-1 prefetch; compute (~2 tiles) covered it
  }

  write_partial(part, bh, sidx, qbase + lo,      hi, a0, a1, a2);
  write_partial(part, bh, sidx, qbase + 32 + lo, hi, b0, b1, b2);
}

// ---------------------------------------------------------------------------
// Finale (wave-cooperative): one wave per (b,n). Lane l -> (h = l>>3, chunk
// c = l&7). Combine 2 splits, per-head Lorentz normalize (shfl_xor 1,2,4),
// head-sum (shfl_xor 8,16,32), final normalize + re-lift.
// ---------------------------------------------------------------------------
__global__ __launch_bounds__(256) void finale_k(const u16* __restrict__ part,
                                                float* __restrict__ out) {
  const int tid = threadIdx.x;
  const int wv = tid >> 6, l = tid & 63;
  const int g = blockIdx.x * 4 + wv;       // 0..8191 = b*2048+n
  const int b = g >> 11, n = g & 2047;
  const int h = l >> 3, c = l & 7;

  const u16* rowp = part + ((size_t)((b * 8 + h) * NS) * Nn + n) * PR;
  float Oh[8];
#pragma unroll
  for (int j = 0; j < 8; ++j) Oh[j] = 0.f;
  float th = 0.f;
#pragma unroll
  for (int s = 0; s < NS; ++s) {
    const u16* rp = rowp + (size_t)s * Nn * PR;
    const u32x4 v = *(const u32x4*)&rp[8 * c];
#pragma unroll
    for (int i = 0; i < 4; ++i) {
      union { u32 u; float f; } a, bb;
      a.u  = v[i] << 16;
      bb.u = v[i] & 0xffff0000u;
      Oh[2 * i]     += a.f;
      Oh[2 * i + 1] += bb.f;
    }
    th += bf2f(rp[64]);
  }

  float sq = 0.f;
#pragma unroll
  for (int j = 0; j < 8; ++j) sq += Oh[j] * Oh[j];
  sq += __shfl_xor(sq, 1);
  sq += __shfl_xor(sq, 2);
  sq += __shfl_xor(sq, 4);
  const float invh = rsqrtf(fmaxf(th * th - sq, 1e-7f));

  float S[8];
#pragma unroll
  for (int j = 0; j < 8; ++j) S[j] = Oh[j] * invh;
  float T = th * invh;
#pragma unroll
  for (int m = 8; m <= 32; m <<= 1) {
#pragma unroll
    for (int j = 0; j < 8; ++j) S[j] += __shfl_xor(S[j], m);
    T += __shfl_xor(T, m);
  }

  float s2 = 0.f;
#pragma unroll
  for (int j = 0; j < 8; ++j) s2 += S[j] * S[j];
  s2 += __shfl_xor(s2, 1);
  s2 += __shfl_xor(s2, 2);
  s2 += __shfl_xor(s2, 4);
  const float inv = rsqrtf(fmaxf(T * T - s2, 1e-7f));
  const float ssp = s2 * inv * inv;        // ||spatial_out||^2

  float* o = out + (size_t)g * AMB;
  if (h == 0) {
#pragma unroll
    for (int j = 0; j < 8; ++j) o[1 + 8 * c + j] = S[j] * inv;
    if (l == 0) o[0] = sqrtf(1.0f + ssp);
  }
}

// ---------------------------------------------------------------------------
extern "C" void kernel_launch(void* const* d_in, const int* in_sizes, int n_in,
                              void* d_out, int out_size, void* d_ws, size_t ws_size,
                              hipStream_t stream) {
  (void)in_sizes; (void)n_in; (void)out_size; (void)ws_size;
  const float* x  = (const float*)d_in[0];
  const float* Wq = (const float*)d_in[1];
  const float* Wk = (const float*)d_in[2];
  const float* Wv = (const float*)d_in[3];
  const float* bq = (const float*)d_in[4];
  const float* bk = (const float*)d_in[5];
  const float* bv = (const float*)d_in[6];
  const float* sc = (const float*)d_in[7];
  // d_in[8] = attn_bias: uniform additive score offset -> softmax-invariant.

  char* ws = (char*)d_ws;
  u16*  Qb  = (u16*)(ws);                  // 10,485,760 B
  u16*  Ktl = (u16*)(ws + 10485760);       // 32*64*6144 = 12,582,912 B
  u16*  Vtl = (u16*)(ws + 23068672);       // 32*64*8192 = 16,777,216 B
  u16*  pb  = (u16*)(ws + 39845888);       // bf16 partials (NS=2): 18,874,368 B
  u16*  xb  = (u16*)(ws + 39845888);       // 2,359,296 B overlay, dead before attn_k
  float* out = (float*)d_out;

  hipLaunchKernelGGL(prep_k, dim3(576), dim3(256), 0, stream, x, xb);
  hipLaunchKernelGGL(proj_k, dim3(32, 24), dim3(256), 0, stream,
                     xb, Wq, Wk, Wv, bq, bk, bv, sc, Qb, Ktl, Vtl);
  hipLaunchKernelGGL(attn_k, dim3(512), dim3(256), 0, stream, Qb, Ktl, Vtl, pb);
  hipLaunchKernelGGL(finale_k, dim3(2048), dim3(256), 0, stream, pb, out);
}